// Round 6
// baseline (84099.829 us; speedup 1.0000x reference)
//
#include <hip/hip_runtime.h>
#include <math.h>

#define BB 8192
#define INW 1024
#define DE 2048
#define NRES 4
#define NE 2048
#define ED 512
#define HID 128
#define ODIM 64
#define NZF (BB*4)
#define EPSLN 1e-5f

// d_out layout: loss, x_hat(B*IN), perplexity, z_q_st(B*DE), idx(NZF)
#define XHAT_OFF 1
#define PERP_OFF (1 + BB*INW)
#define ZQ_OFF   (PERP_OFF + 1)
#define IDX_OFF  (ZQ_OFF + BB*DE)

typedef short bf16x8 __attribute__((ext_vector_type(8)));
typedef float f32x4 __attribute__((ext_vector_type(4)));

__device__ __forceinline__ ushort f2b(float f) {
    unsigned u = __float_as_uint(f);
    unsigned r = (u + 0x7FFFu + ((u >> 16) & 1u)) >> 16;
    return (ushort)r;
}

// async global->LDS, 16B per lane; lds base must be wave-uniform (HW adds lane*16)
__device__ __forceinline__ void gl2lds16(const void* g, void* l) {
    __builtin_amdgcn_global_load_lds(
        (__attribute__((address_space(1))) void*)(g),
        (__attribute__((address_space(3))) void*)(l), 16, 0, 0);
}

// ---------------- prep: xs = (x - shift) / scale (np f32 semantics) ----------------
__global__ __launch_bounds__(256) void prep_xs(const float* __restrict__ x,
    const float* __restrict__ scale, const float* __restrict__ shift,
    float* __restrict__ xs)
{
    const long total = (long)BB*INW;
    for (long g = (long)blockIdx.x*256 + threadIdx.x; g < total; g += (long)gridDim.x*256) {
        int k = (int)(g & (INW-1));
        xs[g] = __fdiv_rn(__fsub_rn(x[g], shift[k]), scale[k]);
    }
}

// ================= fast f32 GEMM, np/BLAS-exact per-element FMA chain =================
// C[m][n] = (sum_k ascending, single fmaf chain) + bias[n].  128x128 tile, 8x8 micro.
// W staged via global_load_lds into unpadded [16][128]; A reg-staged transposed.
template<int HASA2>
__global__ __launch_bounds__(256, 4) void gemm_f32(
    const float* __restrict__ A1, int K1, const float* __restrict__ A2, int K2,
    const float* __restrict__ W, const float* __restrict__ bias,
    float* __restrict__ C, int N)
{
    __shared__ float As[2][16][132];
    __shared__ float Ws[2][16][128];
    const int tid = threadIdx.x;
    const int tx = tid & 15, ty = tid >> 4;
    const int bm = blockIdx.y * 128, bn = blockIdx.x * 128;
    const int K = K1 + K2;
    const int ar = tid >> 1, aq = tid & 1;          // A staging: row, k-half
    const int wv = tid >> 6, lane = tid & 63;       // W staging via lds-DMA
    const int wrow = wv*4 + (lane >> 5);            // tile k-row (+2 for q=1)
    const int wcol = (lane & 31) * 4;               // tile col

    float acc[8][8];
#pragma unroll
    for (int i=0;i<8;i++)
#pragma unroll
      for (int j=0;j<8;j++) acc[i][j] = 0.0f;

    float4 ra0, ra1;
    // prologue: stage tile 0
    gl2lds16(W + (size_t)(wrow    )*N + bn + wcol, &Ws[0][0][0] + wv*512);
    gl2lds16(W + (size_t)(wrow + 2)*N + bn + wcol, &Ws[0][0][0] + wv*512 + 256);
    {
        const float4* p = (const float4*)(A1 + (size_t)(bm+ar)*K1 + aq*8);
        ra0 = p[0]; ra1 = p[1];
        As[0][aq*8+0][ar] = ra0.x; As[0][aq*8+1][ar] = ra0.y;
        As[0][aq*8+2][ar] = ra0.z; As[0][aq*8+3][ar] = ra0.w;
        As[0][aq*8+4][ar] = ra1.x; As[0][aq*8+5][ar] = ra1.y;
        As[0][aq*8+6][ar] = ra1.z; As[0][aq*8+7][ar] = ra1.w;
    }
    __syncthreads();

    int cur = 0;
    for (int k0 = 0; k0 < K; k0 += 16) {
        int kn = k0 + 16;
        int nb = cur ^ 1;
        if (kn < K) {
            // W -> LDS DMA (async, lands before next barrier)
            gl2lds16(W + (size_t)(kn + wrow    )*N + bn + wcol, &Ws[nb][0][0] + wv*512);
            gl2lds16(W + (size_t)(kn + wrow + 2)*N + bn + wcol, &Ws[nb][0][0] + wv*512 + 256);
            // A -> regs
            const float* s;
            if (HASA2 && kn >= K1) s = A2 + (size_t)(bm+ar)*K2 + (kn - K1) + aq*8;
            else                   s = A1 + (size_t)(bm+ar)*K1 + kn + aq*8;
            const float4* p = (const float4*)s;
            ra0 = p[0]; ra1 = p[1];
        }
#pragma unroll
        for (int kk = 0; kk < 16; ++kk) {
            float4 va0 = *(const float4*)&As[cur][kk][ty*4];
            float4 va1 = *(const float4*)&As[cur][kk][64 + ty*4];
            float4 vb0 = *(const float4*)&Ws[cur][kk][tx*4];
            float4 vb1 = *(const float4*)&Ws[cur][kk][64 + tx*4];
            float av[8] = {va0.x,va0.y,va0.z,va0.w, va1.x,va1.y,va1.z,va1.w};
            float bv[8] = {vb0.x,vb0.y,vb0.z,vb0.w, vb1.x,vb1.y,vb1.z,vb1.w};
#pragma unroll
            for (int i=0;i<8;i++)
#pragma unroll
                for (int j=0;j<8;j++)
                    acc[i][j] = fmaf(av[i], bv[j], acc[i][j]);
        }
        if (kn < K) {
            As[nb][aq*8+0][ar] = ra0.x; As[nb][aq*8+1][ar] = ra0.y;
            As[nb][aq*8+2][ar] = ra0.z; As[nb][aq*8+3][ar] = ra0.w;
            As[nb][aq*8+4][ar] = ra1.x; As[nb][aq*8+5][ar] = ra1.y;
            As[nb][aq*8+6][ar] = ra1.z; As[nb][aq*8+7][ar] = ra1.w;
        }
        __syncthreads();
        cur ^= 1;
    }
    // epilogue
    float4 bv0 = *(const float4*)&bias[bn + tx*4];
    float4 bv1 = *(const float4*)&bias[bn + 64 + tx*4];
    const float bb[8] = {bv0.x,bv0.y,bv0.z,bv0.w, bv1.x,bv1.y,bv1.z,bv1.w};
#pragma unroll
    for (int i=0;i<8;i++) {
        int gm = bm + ((i<4) ? ty*4+i : 64 + ty*4 + (i-4));
        float4 o0, o1;
        o0.x = __fadd_rn(acc[i][0], bb[0]); o0.y = __fadd_rn(acc[i][1], bb[1]);
        o0.z = __fadd_rn(acc[i][2], bb[2]); o0.w = __fadd_rn(acc[i][3], bb[3]);
        o1.x = __fadd_rn(acc[i][4], bb[4]); o1.y = __fadd_rn(acc[i][5], bb[5]);
        o1.z = __fadd_rn(acc[i][6], bb[6]); o1.w = __fadd_rn(acc[i][7], bb[7]);
        *(float4*)&C[(size_t)gm*N + bn + tx*4]      = o0;
        *(float4*)&C[(size_t)gm*N + bn + 64 + tx*4] = o1;
    }
}

// ---------------- codebook transpose (exact copy): cbT[e][c] = cb[c][e] ----------------
__global__ __launch_bounds__(256) void transCB(const float* __restrict__ cbk,
    float* __restrict__ cbT)
{
    __shared__ float tile[32][33];
    int c0 = blockIdx.x*32, e0 = blockIdx.y*32;
    int txx = threadIdx.x & 31, tyy = threadIdx.x >> 5;
#pragma unroll
    for (int i=0;i<4;i++)
        tile[tyy + i*8][txx] = cbk[(size_t)(c0 + tyy + i*8)*ED + e0 + txx];
    __syncthreads();
#pragma unroll
    for (int i=0;i<4;i++)
        cbT[(size_t)(e0 + tyy + i*8)*NE + c0 + txx] = tile[txx][tyy + i*8];
}

// ================= fused VQ: 128x128 dists + shuffle first-min partial argmin =================
__global__ __launch_bounds__(256, 4) void vq128(const float* __restrict__ zf,
    const float* __restrict__ cbT, const float* __restrict__ sz, const float* __restrict__ sc,
    float* __restrict__ pval, int* __restrict__ pidx)
{
    __shared__ float Zs[2][16][132];
    __shared__ float Cs[2][16][128];
    const int tid = threadIdx.x;
    const int tx = tid & 15, ty = tid >> 4;
    const int br = blockIdx.y * 128, bc = blockIdx.x * 128;
    const int ar = tid >> 1, aq = tid & 1;
    const int wv = tid >> 6, lane = tid & 63;
    const int wrow = wv*4 + (lane >> 5);
    const int wcol = (lane & 31) * 4;

    float acc[8][8];
#pragma unroll
    for (int i=0;i<8;i++)
#pragma unroll
      for (int j=0;j<8;j++) acc[i][j] = 0.0f;

    float4 ra0, ra1;
    gl2lds16(cbT + (size_t)(wrow    )*NE + bc + wcol, &Cs[0][0][0] + wv*512);
    gl2lds16(cbT + (size_t)(wrow + 2)*NE + bc + wcol, &Cs[0][0][0] + wv*512 + 256);
    {
        const float4* p = (const float4*)(zf + (size_t)(br+ar)*ED + aq*8);
        ra0 = p[0]; ra1 = p[1];
        Zs[0][aq*8+0][ar] = ra0.x; Zs[0][aq*8+1][ar] = ra0.y;
        Zs[0][aq*8+2][ar] = ra0.z; Zs[0][aq*8+3][ar] = ra0.w;
        Zs[0][aq*8+4][ar] = ra1.x; Zs[0][aq*8+5][ar] = ra1.y;
        Zs[0][aq*8+6][ar] = ra1.z; Zs[0][aq*8+7][ar] = ra1.w;
    }
    __syncthreads();

    int cur = 0;
    for (int k0 = 0; k0 < ED; k0 += 16) {
        int kn = k0 + 16;
        int nb = cur ^ 1;
        if (kn < ED) {
            gl2lds16(cbT + (size_t)(kn + wrow    )*NE + bc + wcol, &Cs[nb][0][0] + wv*512);
            gl2lds16(cbT + (size_t)(kn + wrow + 2)*NE + bc + wcol, &Cs[nb][0][0] + wv*512 + 256);
            const float4* p = (const float4*)(zf + (size_t)(br+ar)*ED + kn + aq*8);
            ra0 = p[0]; ra1 = p[1];
        }
#pragma unroll
        for (int kk = 0; kk < 16; ++kk) {
            float4 va0 = *(const float4*)&Zs[cur][kk][ty*4];
            float4 va1 = *(const float4*)&Zs[cur][kk][64 + ty*4];
            float4 vb0 = *(const float4*)&Cs[cur][kk][tx*4];
            float4 vb1 = *(const float4*)&Cs[cur][kk][64 + tx*4];
            float av[8] = {va0.x,va0.y,va0.z,va0.w, va1.x,va1.y,va1.z,va1.w};
            float bv[8] = {vb0.x,vb0.y,vb0.z,vb0.w, vb1.x,vb1.y,vb1.z,vb1.w};
#pragma unroll
            for (int i=0;i<8;i++)
#pragma unroll
                for (int j=0;j<8;j++)
                    acc[i][j] = fmaf(av[i], bv[j], acc[i][j]);
        }
        if (kn < ED) {
            Zs[nb][aq*8+0][ar] = ra0.x; Zs[nb][aq*8+1][ar] = ra0.y;
            Zs[nb][aq*8+2][ar] = ra0.z; Zs[nb][aq*8+3][ar] = ra0.w;
            Zs[nb][aq*8+4][ar] = ra1.x; Zs[nb][aq*8+5][ar] = ra1.y;
            Zs[nb][aq*8+6][ar] = ra1.z; Zs[nb][aq*8+7][ar] = ra1.w;
        }
        __syncthreads();
        cur ^= 1;
    }
    // dists + first-min: per-thread over its 8 cols, then 16-lane shuffle tree.
    // lexicographic (val, idx) min == np.argmin first-min semantics.
#pragma unroll
    for (int i=0;i<8;i++) {
        int lr = (i<4) ? ty*4+i : 64 + ty*4 + (i-4);
        float szi = sz[br + lr];
        float bvv = 0.0f; int bii = -1;
#pragma unroll
        for (int j=0;j<8;j++) {
            int lc = (j<4) ? tx*4+j : 64 + tx*4 + (j-4);
            int gc = bc + lc;
            float d = __fsub_rn(__fadd_rn(szi, sc[gc]), __fmul_rn(2.0f, acc[i][j]));
            if (bii < 0 || d < bvv || (d == bvv && gc < bii)) { bvv = d; bii = gc; }
        }
#pragma unroll
        for (int off = 8; off; off >>= 1) {
            float ov = __shfl_xor(bvv, off);
            int   oi = __shfl_xor(bii, off);
            if (ov < bvv || (ov == bvv && oi < bii)) { bvv = ov; bii = oi; }
        }
        if (tx == 0) {
            pval[(size_t)(br+lr)*16 + blockIdx.x] = bvv;
            pidx[(size_t)(br+lr)*16 + blockIdx.x] = bii;
        }
    }
}

// ================= bf16 MFMA GEMM (decoder only; loose thresholds) =================
template<int EPI>
__global__ __launch_bounds__(256) void gemm_bf16(
    const ushort* __restrict__ X, const ushort* __restrict__ WT,
    const float* __restrict__ bias, const float* __restrict__ esc,
    const float* __restrict__ esh, float* __restrict__ C,
    ushort* __restrict__ Cb, int N, int K)
{
    __shared__ ushort Xs[2][128][40];
    __shared__ ushort Ws[2][128][40];
    const int tid = threadIdx.x;
    const int lane = tid & 63, wave = tid >> 6;
    const int wr = wave >> 1, wc = wave & 1;
    const int bm = blockIdx.y * 128, bn = blockIdx.x * 128;
    const int sr = tid >> 1, sh = tid & 1;

    f32x4 acc[4][4];
#pragma unroll
    for (int m=0;m<4;m++)
#pragma unroll
      for (int n=0;n<4;n++) acc[m][n] = (f32x4){0.f,0.f,0.f,0.f};

    float4 xv0, xv1, wv0, wv1;
    {
        const float4* xp = (const float4*)(X + (size_t)(bm+sr)*K + sh*16);
        xv0 = xp[0]; xv1 = xp[1];
        const float4* wp = (const float4*)(WT + (size_t)(bn+sr)*K + sh*16);
        wv0 = wp[0]; wv1 = wp[1];
    }
    {
        float4* dx = (float4*)&Xs[0][sr][sh*16]; dx[0] = xv0; dx[1] = xv1;
        float4* dw = (float4*)&Ws[0][sr][sh*16]; dw[0] = wv0; dw[1] = wv1;
    }
    __syncthreads();

    const int ko = (lane >> 4) * 8;
    const int fr = lane & 15;
    int cur = 0;
    for (int k0 = 0; k0 < K; k0 += 32) {
        int kn = k0 + 32;
        if (kn < K) {
            const float4* xp = (const float4*)(X + (size_t)(bm+sr)*K + kn + sh*16);
            xv0 = xp[0]; xv1 = xp[1];
            const float4* wp = (const float4*)(WT + (size_t)(bn+sr)*K + kn + sh*16);
            wv0 = wp[0]; wv1 = wp[1];
        }
        bf16x8 af[4], bfr[4];
#pragma unroll
        for (int m=0;m<4;m++) af[m]  = *(const bf16x8*)&Xs[cur][wr*64 + m*16 + fr][ko];
#pragma unroll
        for (int n=0;n<4;n++) bfr[n] = *(const bf16x8*)&Ws[cur][wc*64 + n*16 + fr][ko];
#pragma unroll
        for (int m=0;m<4;m++)
#pragma unroll
            for (int n=0;n<4;n++)
                acc[m][n] = __builtin_amdgcn_mfma_f32_16x16x32_bf16(af[m], bfr[n], acc[m][n], 0, 0, 0);
        if (kn < K) {
            int nb = cur ^ 1;
            float4* dx = (float4*)&Xs[nb][sr][sh*16]; dx[0] = xv0; dx[1] = xv1;
            float4* dw = (float4*)&Ws[nb][sr][sh*16]; dw[0] = wv0; dw[1] = wv1;
        }
        __syncthreads();
        cur ^= 1;
    }
    const int cr = (lane >> 4) * 4, cc = lane & 15;
#pragma unroll
    for (int m=0;m<4;m++) {
#pragma unroll
        for (int n=0;n<4;n++) {
            int gn = bn + wc*64 + n*16 + cc;
            float bb = bias[gn];
            float s0 = 0.f, s1 = 0.f;
            if (EPI == 1) { s0 = esc[gn]; s1 = esh[gn]; }
#pragma unroll
            for (int r=0;r<4;r++) {
                int gm = bm + wr*64 + m*16 + cr + r;
                float v = acc[m][n][r] + bb;
                if (EPI == 1) v = s0*v + s1;
                size_t off = (size_t)gm*N + gn;
                C[off] = v;
                if (EPI == 2) Cb[off] = f2b(v);
            }
        }
    }
}

// ---------------- weight transpose + f32->bf16: WT[n][k] = bf16(W[k][n]) ----------------
__global__ __launch_bounds__(256) void transW(const float* __restrict__ W,
    ushort* __restrict__ WT, int K, int N)
{
    __shared__ float tile[32][33];
    int n0 = blockIdx.x*32, k0 = blockIdx.y*32;
    int tx = threadIdx.x & 31, ty8 = threadIdx.x >> 5;
#pragma unroll
    for (int i=0;i<4;i++)
        tile[ty8 + i*8][tx] = W[(size_t)(k0 + ty8 + i*8)*N + n0 + tx];
    __syncthreads();
#pragma unroll
    for (int i=0;i<4;i++) {
        int n = ty8 + i*8;
        WT[(size_t)(n0+n)*K + k0 + tx] = f2b(tile[tx][n]);
    }
}

// ---------------- LayerNorm + relu + add, numpy-f32-exact; WB=1 also writes bf16 mirror ----------------
template<int WB>
__global__ __launch_bounds__(64) void ln_np(const float* __restrict__ t,
    float* __restrict__ h, ushort* __restrict__ hb,
    const float* __restrict__ g, const float* __restrict__ be)
{
    const int row = blockIdx.x;
    const float* tr = t + (long)row*DE;
    float* hr = h + (long)row*DE;
    __shared__ float bs[16];
    __shared__ float mv[2];
    const int l = threadIdx.x;

    if (l < 16) {
        const float* p = tr + l*128;
        float r[8];
#pragma unroll
        for (int j=0;j<8;j++) r[j] = p[j];
        for (int i=8;i<128;i+=8)
#pragma unroll
            for (int j=0;j<8;j++) r[j] = __fadd_rn(r[j], p[i+j]);
        float tA = __fadd_rn(__fadd_rn(r[0],r[1]), __fadd_rn(r[2],r[3]));
        float tB = __fadd_rn(__fadd_rn(r[4],r[5]), __fadd_rn(r[6],r[7]));
        bs[l] = __fadd_rn(tA, tB);
    }
    __syncthreads();
    if (l == 0) {
        float s8[8], s4[4], s2[2];
#pragma unroll
        for (int i=0;i<8;i++) s8[i] = __fadd_rn(bs[2*i], bs[2*i+1]);
#pragma unroll
        for (int i=0;i<4;i++) s4[i] = __fadd_rn(s8[2*i], s8[2*i+1]);
#pragma unroll
        for (int i=0;i<2;i++) s2[i] = __fadd_rn(s4[2*i], s4[2*i+1]);
        mv[0] = __fdiv_rn(__fadd_rn(s2[0], s2[1]), 2048.0f);
    }
    __syncthreads();
    const float m = mv[0];
    if (l < 16) {
        const float* p = tr + l*128;
        float r[8];
#pragma unroll
        for (int j=0;j<8;j++) { float d = __fsub_rn(p[j], m); r[j] = __fmul_rn(d, d); }
        for (int i=8;i<128;i+=8)
#pragma unroll
            for (int j=0;j<8;j++) {
                float d = __fsub_rn(p[i+j], m);
                r[j] = __fadd_rn(r[j], __fmul_rn(d, d));
            }
        float tA = __fadd_rn(__fadd_rn(r[0],r[1]), __fadd_rn(r[2],r[3]));
        float tB = __fadd_rn(__fadd_rn(r[4],r[5]), __fadd_rn(r[6],r[7]));
        bs[l] = __fadd_rn(tA, tB);
    }
    __syncthreads();
    if (l == 0) {
        float s8[8], s4[4], s2[2];
#pragma unroll
        for (int i=0;i<8;i++) s8[i] = __fadd_rn(bs[2*i], bs[2*i+1]);
#pragma unroll
        for (int i=0;i<4;i++) s4[i] = __fadd_rn(s8[2*i], s8[2*i+1]);
#pragma unroll
        for (int i=0;i<2;i++) s2[i] = __fadd_rn(s4[2*i], s4[2*i+1]);
        float v = __fdiv_rn(__fadd_rn(s2[0], s2[1]), 2048.0f);
        mv[1] = __fdiv_rn(1.0f, __fsqrt_rn(__fadd_rn(v, EPSLN)));
    }
    __syncthreads();
    const float rs = mv[1];
    ushort* hbr = (WB ? hb + (long)row*DE : nullptr);
    for (int j = l; j < DE; j += 64) {
        float u = __fadd_rn(__fmul_rn(__fmul_rn(__fsub_rn(tr[j], m), rs), g[j]), be[j]);
        float r = u > 0.0f ? u : 0.0f;
        float nh = __fadd_rn(hr[j], r);
        hr[j] = nh;
        if (WB) hbr[j] = f2b(nh);
    }
}

// ---------------- IdxEmbedding, np-f32 ----------------
__global__ __launch_bounds__(128) void idx_embed_np(const int* __restrict__ bidx,
    const float* __restrict__ lay, const float* __restrict__ lty, const float* __restrict__ wty,
    const float* __restrict__ fw, const float* __restrict__ fb,
    const float* __restrict__ ow, const float* __restrict__ ob,
    float* __restrict__ oidx)
{
    const int row = blockIdx.x;
    __shared__ float emb[3*HID+3];
    __shared__ float fcv[HID];
    const int t = threadIdx.x;
    int c0 = bidx[row*6+0], c1 = bidx[row*6+1], c2 = bidx[row*6+2];
    emb[t]       = lay[c0*HID + t];
    emb[HID+t]   = lty[c1*HID + t];
    emb[2*HID+t] = wty[c2*HID + t];
    if (t < 3) emb[3*HID+t] = (float)bidx[row*6+3+t];
    __syncthreads();
    {
        float acc = 0.0f;
        for (int k = 0; k < 3*HID+3; ++k)
            acc = fmaf(emb[k], fw[k*HID + t], acc);
        fcv[t] = __fadd_rn(acc, fb[t]);
    }
    __syncthreads();
    if (t < ODIM) {
        float acc = 0.0f;
        for (int k = 0; k < HID; ++k)
            acc = fmaf(fcv[k], ow[k*ODIM + t], acc);
        oidx[(long)row*ODIM + t] = __fadd_rn(acc, ob[t]);
    }
}

// ---------------- squared row norms, numpy pairwise (4 blocks of 128) ----------------
__global__ __launch_bounds__(256) void sqnorm_np(const float* __restrict__ a, int nrows,
    float* __restrict__ outv)
{
    int rI = blockIdx.x*256 + threadIdx.x;
    if (rI >= nrows) return;
    const float* p = a + (long)rI*ED;
    float B[4];
#pragma unroll
    for (int b = 0; b < 4; ++b) {
        const float* q = p + b*128;
        float r[8];
#pragma unroll
        for (int j=0;j<8;j++) r[j] = __fmul_rn(q[j], q[j]);
        for (int i=8;i<128;i+=8)
#pragma unroll
            for (int j=0;j<8;j++) r[j] = __fadd_rn(r[j], __fmul_rn(q[i+j], q[i+j]));
        float tA = __fadd_rn(__fadd_rn(r[0],r[1]), __fadd_rn(r[2],r[3]));
        float tB = __fadd_rn(__fadd_rn(r[4],r[5]), __fadd_rn(r[6],r[7]));
        B[b] = __fadd_rn(tA, tB);
    }
    outv[rI] = __fadd_rn(__fadd_rn(B[0], B[1]), __fadd_rn(B[2], B[3]));
}

// ---------------- final argmin across 16 column blocks ----------------
__global__ __launch_bounds__(256) void vq_reduce(const float* __restrict__ pval,
    const int* __restrict__ pidx, int* __restrict__ idxw, float* __restrict__ idxf,
    int* __restrict__ cnt)
{
    int r = blockIdx.x*256 + threadIdx.x;
    const float* pv = pval + (long)r*16;
    const int*   pi = pidx + (long)r*16;
    float best = pv[0]; int bj = pi[0];
#pragma unroll
    for (int c = 1; c < 16; ++c) {
        float v = pv[c]; int ii = pi[c];
        if (v < best || (v == best && ii < bj)) { best = v; bj = ii; }
    }
    idxw[r] = bj;
    idxf[r] = (float)bj;
    atomicAdd(&cnt[bj], 1);
}

// ---------------- z_q_st + bf16 mirror + SSE accumulation ----------------
__global__ __launch_bounds__(256) void zq_loss(const int* __restrict__ idxw,
    const float* __restrict__ cbk, const float* __restrict__ z_e,
    float* __restrict__ zq_out, ushort* __restrict__ zqb, double* __restrict__ sse)
{
    double local = 0.0;
    const long total = (long)NZF*ED;
    for (long g = (long)blockIdx.x*256 + threadIdx.x; g < total; g += (long)gridDim.x*256) {
        int p = (int)(g >> 9);
        int e = (int)(g & 511);
        float q = cbk[(long)idxw[p]*ED + e];
        float z = z_e[g];
        float d = __fsub_rn(q, z);
        float o = __fadd_rn(z, d);
        zq_out[g] = o;
        zqb[g] = f2b(o);
        local += (double)d * (double)d;
    }
    for (int off = 32; off > 0; off >>= 1) local += __shfl_down(local, off);
    __shared__ double red[4];
    int wid = threadIdx.x >> 6, lane = threadIdx.x & 63;
    if (lane == 0) red[wid] = local;
    __syncthreads();
    if (threadIdx.x == 0) atomicAdd(sse, red[0]+red[1]+red[2]+red[3]);
}

// ---------------- loss + perplexity ----------------
__global__ __launch_bounds__(256) void finalize(const int* __restrict__ cnt,
    const double* __restrict__ sse, float* __restrict__ d_out)
{
    double s = 0.0;
    for (int j = threadIdx.x; j < NE; j += 256) {
        double e = (double)cnt[j] / (double)NZF;
        s += e * log(e + 1e-10);
    }
    for (int off = 32; off > 0; off >>= 1) s += __shfl_down(s, off);
    __shared__ double red[4];
    int wid = threadIdx.x >> 6, lane = threadIdx.x & 63;
    if (lane == 0) red[wid] = s;
    __syncthreads();
    if (threadIdx.x == 0) {
        double st = red[0]+red[1]+red[2]+red[3];
        d_out[0]        = (float)(1.25 * sse[0] / (double)((long)BB*DE));
        d_out[PERP_OFF] = (float)exp(-st);
    }
}

extern "C" void kernel_launch(void* const* d_in, const int* in_sizes, int n_in,
                              void* d_out_v, int out_size, void* d_ws, size_t ws_size,
                              hipStream_t stream)
{
    const float* x         = (const float*)d_in[0];
    const int*   bidx      = (const int*)  d_in[1];
    const float* scale     = (const float*)d_in[2];
    const float* shift     = (const float*)d_in[3];
    const float* enc_in_w  = (const float*)d_in[4];
    const float* enc_in_b  = (const float*)d_in[5];
    const float* enc_res_w = (const float*)d_in[6];
    const float* enc_res_b = (const float*)d_in[7];
    const float* enc_ln_g  = (const float*)d_in[8];
    const float* enc_ln_b  = (const float*)d_in[9];
    const float* lay       = (const float*)d_in[10];
    const float* lty       = (const float*)d_in[11];
    const float* wty       = (const float*)d_in[12];
    const float* fcw       = (const float*)d_in[13];
    const float* fcb       = (const float*)d_in[14];
    const float* oww       = (const float*)d_in[15];
    const float* owb       = (const float*)d_in[16];
    const float* catw      = (const float*)d_in[17];
    const float* catb      = (const float*)d_in[18];
    const float* cbk       = (const float*)d_in[19];
    const float* dec_in_w  = (const float*)d_in[20];
    const float* dec_in_b  = (const float*)d_in[21];
    const float* dec_res_w = (const float*)d_in[22];
    const float* dec_res_b = (const float*)d_in[23];
    const float* dec_ln_g  = (const float*)d_in[24];
    const float* dec_ln_b  = (const float*)d_in[25];
    const float* dec_out_w = (const float*)d_in[26];
    const float* dec_out_b = (const float*)d_in[27];
    float* out = (float*)d_out_v;

    char* w = (char*)d_ws;
    auto alloc = [&](size_t bytes) {
        char* p = w;
        w += (bytes + 255) & ~(size_t)255;
        return p;
    };
    float*  xs   = (float*)alloc((size_t)BB*INW*4);     // dead after enc_in GEMM
    float*  h    = (float*)alloc((size_t)BB*DE*4);
    float*  t    = (float*)alloc((size_t)BB*DE*4);
    float*  oidx = (float*)alloc((size_t)BB*ODIM*4);
    int*    idxw = (int*)  alloc((size_t)NZF*4);
    float*  szv  = (float*)alloc((size_t)NZF*4);
    float*  scv  = (float*)alloc((size_t)NE*4);
    int*    cnt  = (int*)  alloc((size_t)NE*4);
    double* sse  = (double*)alloc(8);
    float*  cbT  = (float*)alloc((size_t)ED*NE*4);      // 4MB transposed codebook
    ushort* zqb  = (ushort*)alloc((size_t)BB*DE*2);     // bf16 z_q_st
    ushort* hb   = (ushort*)alloc((size_t)BB*DE*2);     // bf16 decoder hidden
    ushort* wt1  = (ushort*)alloc((size_t)DE*DE*2);     // dec_in_w^T bf16
    ushort* wt2  = (ushort*)alloc((size_t)DE*DE*2);     // dec_res_w^T bf16
    ushort* wt3  = (ushort*)alloc((size_t)INW*DE*2);    // dec_out_w^T bf16
    // aliases:
    float*  z_e  = t;
    float*  pval = (float*)xs;                          // NZF*16*4 (xs dead)
    int*    pidx = (int*)(xs + (size_t)NZF*16);

    hipMemsetAsync(cnt, 0, (size_t)NE*4, stream);
    hipMemsetAsync(sse, 0, 8, stream);

    dim3 gDE(DE/128, BB/128);    // (16,64)
    dim3 gIN(INW/128, BB/128);   // (8,64)
    dim3 gVQ(NE/128, NZF/128);   // (16,256)

    // ---- encoder: numpy-f32-exact semantics ----
    prep_xs<<<2048, 256, 0, stream>>>(x, scale, shift, xs);
    gemm_f32<0><<<gDE, 256, 0, stream>>>(xs, INW, nullptr, 0, enc_in_w, enc_in_b, h, DE);
    for (int r = 0; r < NRES; ++r) {
        gemm_f32<0><<<gDE, 256, 0, stream>>>(h, DE, nullptr, 0, enc_res_w, enc_res_b, t, DE);
        ln_np<0><<<BB, 64, 0, stream>>>(t, h, nullptr, enc_ln_g, enc_ln_b);
    }
    idx_embed_np<<<BB, 128, 0, stream>>>(bidx, lay, lty, wty, fcw, fcb, oww, owb, oidx);
    gemm_f32<1><<<gDE, 256, 0, stream>>>(h, DE, oidx, ODIM, catw, catb, z_e, DE);
    // ---- VQ: numpy-f32 dists + first-min argmin ----
    transCB<<<dim3(NE/32, ED/32), 256, 0, stream>>>(cbk, cbT);
    sqnorm_np<<<NZF/256, 256, 0, stream>>>(z_e, NZF, szv);
    sqnorm_np<<<NE/256, 256, 0, stream>>>(cbk, NE, scv);
    vq128<<<gVQ, 256, 0, stream>>>(z_e, cbT, szv, scv, pval, pidx);
    vq_reduce<<<NZF/256, 256, 0, stream>>>(pval, pidx, idxw, out + IDX_OFF, cnt);
    zq_loss<<<2048, 256, 0, stream>>>(idxw, cbk, z_e, out + ZQ_OFF, zqb, sse);
    finalize<<<1, 256, 0, stream>>>(cnt, sse, out);
    // ---- decoder: bf16 MFMA (loose thresholds) ----
    transW<<<dim3(DE/32, DE/32), 256, 0, stream>>>(dec_in_w,  wt1, DE, DE);
    transW<<<dim3(DE/32, DE/32), 256, 0, stream>>>(dec_res_w, wt2, DE, DE);
    transW<<<dim3(INW/32, DE/32), 256, 0, stream>>>(dec_out_w, wt3, DE, INW);
    gemm_bf16<2><<<gDE, 256, 0, stream>>>(zqb, wt1, dec_in_b, nullptr, nullptr, h, hb, DE, DE);
    for (int r = 0; r < NRES; ++r) {
        gemm_bf16<0><<<gDE, 256, 0, stream>>>(hb, wt2, dec_res_b, nullptr, nullptr, t, nullptr, DE, DE);
        ln_np<1><<<BB, 64, 0, stream>>>(t, h, hb, dec_ln_g, dec_ln_b);
    }
    gemm_bf16<1><<<gIN, 256, 0, stream>>>(hb, wt3, dec_out_b, scale, shift, out + XHAT_OFF, nullptr, INW, DE);
}

// Round 7
// 55382.007 us; speedup vs baseline: 1.5185x; 1.5185x over previous
//
#include <hip/hip_runtime.h>
#include <math.h>

#define BB 8192
#define INW 1024
#define DE 2048
#define NRES 4
#define NE 2048
#define ED 512
#define HID 128
#define ODIM 64
#define NZF (BB*4)
#define EPSLN 1e-5f

// d_out layout: loss, x_hat(B*IN), perplexity, z_q_st(B*DE), idx(NZF)
#define XHAT_OFF 1
#define PERP_OFF (1 + BB*INW)
#define ZQ_OFF   (PERP_OFF + 1)
#define IDX_OFF  (ZQ_OFF + BB*DE)

typedef short bf16x8 __attribute__((ext_vector_type(8)));
typedef float f32x4 __attribute__((ext_vector_type(4)));

__device__ __forceinline__ ushort f2b(float f) {
    unsigned u = __float_as_uint(f);
    unsigned r = (u + 0x7FFFu + ((u >> 16) & 1u)) >> 16;
    return (ushort)r;
}

// async global->LDS, 16B per lane; lds base must be wave-uniform (HW adds lane*16)
__device__ __forceinline__ void gl2lds16(const void* g, void* l) {
    __builtin_amdgcn_global_load_lds(
        (__attribute__((address_space(1))) void*)(g),
        (__attribute__((address_space(3))) void*)(l), 16, 0, 0);
}

// ---------------- prep: xs = (x - shift) / scale (np f32 semantics) ----------------
__global__ __launch_bounds__(256) void prep_xs(const float* __restrict__ x,
    const float* __restrict__ scale, const float* __restrict__ shift,
    float* __restrict__ xs)
{
    const long total = (long)BB*INW;
    for (long g = (long)blockIdx.x*256 + threadIdx.x; g < total; g += (long)gridDim.x*256) {
        int k = (int)(g & (INW-1));
        xs[g] = __fdiv_rn(__fsub_rn(x[g], shift[k]), scale[k]);
    }
}

// ================= fast f32 GEMM, np/BLAS-exact per-element FMA chain =================
// C[m][n] = (sum_k ascending, single fmaf chain) + bias[n].  128x128 tile, 8x8 micro.
// W staged via global_load_lds into unpadded [16][128]; A reg-staged transposed.
// launch_bounds(256,3): VGPR cap ~170 -> 3 waves/SIMD, no spill (round-6 (256,4)=128 spilled).
template<int HASA2>
__global__ __launch_bounds__(256, 3) void gemm_f32(
    const float* __restrict__ A1, int K1, const float* __restrict__ A2, int K2,
    const float* __restrict__ W, const float* __restrict__ bias,
    float* __restrict__ C, int N)
{
    __shared__ float As[2][16][132];
    __shared__ float Ws[2][16][128];
    const int tid = threadIdx.x;
    const int tx = tid & 15, ty = tid >> 4;
    const int bm = blockIdx.y * 128, bn = blockIdx.x * 128;
    const int K = K1 + K2;
    const int ar = tid >> 1, aq = tid & 1;          // A staging: row, k-half
    const int wv = tid >> 6, lane = tid & 63;       // W staging via lds-DMA
    const int wrow = wv*4 + (lane >> 5);            // tile k-row (+2 for q=1)
    const int wcol = (lane & 31) * 4;               // tile col

    float acc[8][8];
#pragma unroll
    for (int i=0;i<8;i++)
#pragma unroll
      for (int j=0;j<8;j++) acc[i][j] = 0.0f;

    float4 ra0, ra1;
    // prologue: stage tile 0
    gl2lds16(W + (size_t)(wrow    )*N + bn + wcol, &Ws[0][0][0] + wv*512);
    gl2lds16(W + (size_t)(wrow + 2)*N + bn + wcol, &Ws[0][0][0] + wv*512 + 256);
    {
        const float4* p = (const float4*)(A1 + (size_t)(bm+ar)*K1 + aq*8);
        ra0 = p[0]; ra1 = p[1];
        As[0][aq*8+0][ar] = ra0.x; As[0][aq*8+1][ar] = ra0.y;
        As[0][aq*8+2][ar] = ra0.z; As[0][aq*8+3][ar] = ra0.w;
        As[0][aq*8+4][ar] = ra1.x; As[0][aq*8+5][ar] = ra1.y;
        As[0][aq*8+6][ar] = ra1.z; As[0][aq*8+7][ar] = ra1.w;
    }
    __syncthreads();

    int cur = 0;
    for (int k0 = 0; k0 < K; k0 += 16) {
        int kn = k0 + 16;
        int nb = cur ^ 1;
        if (kn < K) {
            // W -> LDS DMA (async, lands before next barrier)
            gl2lds16(W + (size_t)(kn + wrow    )*N + bn + wcol, &Ws[nb][0][0] + wv*512);
            gl2lds16(W + (size_t)(kn + wrow + 2)*N + bn + wcol, &Ws[nb][0][0] + wv*512 + 256);
            // A -> regs
            const float* s;
            if (HASA2 && kn >= K1) s = A2 + (size_t)(bm+ar)*K2 + (kn - K1) + aq*8;
            else                   s = A1 + (size_t)(bm+ar)*K1 + kn + aq*8;
            const float4* p = (const float4*)s;
            ra0 = p[0]; ra1 = p[1];
        }
#pragma unroll
        for (int kk = 0; kk < 16; ++kk) {
            float4 va0 = *(const float4*)&As[cur][kk][ty*4];
            float4 va1 = *(const float4*)&As[cur][kk][64 + ty*4];
            float4 vb0 = *(const float4*)&Ws[cur][kk][tx*4];
            float4 vb1 = *(const float4*)&Ws[cur][kk][64 + tx*4];
            float av[8] = {va0.x,va0.y,va0.z,va0.w, va1.x,va1.y,va1.z,va1.w};
            float bv[8] = {vb0.x,vb0.y,vb0.z,vb0.w, vb1.x,vb1.y,vb1.z,vb1.w};
#pragma unroll
            for (int i=0;i<8;i++)
#pragma unroll
                for (int j=0;j<8;j++)
                    acc[i][j] = fmaf(av[i], bv[j], acc[i][j]);
        }
        if (kn < K) {
            As[nb][aq*8+0][ar] = ra0.x; As[nb][aq*8+1][ar] = ra0.y;
            As[nb][aq*8+2][ar] = ra0.z; As[nb][aq*8+3][ar] = ra0.w;
            As[nb][aq*8+4][ar] = ra1.x; As[nb][aq*8+5][ar] = ra1.y;
            As[nb][aq*8+6][ar] = ra1.z; As[nb][aq*8+7][ar] = ra1.w;
        }
        __syncthreads();
        cur ^= 1;
    }
    // epilogue
    float4 bv0 = *(const float4*)&bias[bn + tx*4];
    float4 bv1 = *(const float4*)&bias[bn + 64 + tx*4];
    const float bb[8] = {bv0.x,bv0.y,bv0.z,bv0.w, bv1.x,bv1.y,bv1.z,bv1.w};
#pragma unroll
    for (int i=0;i<8;i++) {
        int gm = bm + ((i<4) ? ty*4+i : 64 + ty*4 + (i-4));
        float4 o0, o1;
        o0.x = __fadd_rn(acc[i][0], bb[0]); o0.y = __fadd_rn(acc[i][1], bb[1]);
        o0.z = __fadd_rn(acc[i][2], bb[2]); o0.w = __fadd_rn(acc[i][3], bb[3]);
        o1.x = __fadd_rn(acc[i][4], bb[4]); o1.y = __fadd_rn(acc[i][5], bb[5]);
        o1.z = __fadd_rn(acc[i][6], bb[6]); o1.w = __fadd_rn(acc[i][7], bb[7]);
        *(float4*)&C[(size_t)gm*N + bn + tx*4]      = o0;
        *(float4*)&C[(size_t)gm*N + bn + 64 + tx*4] = o1;
    }
}

// ---------------- codebook transpose (exact copy): cbT[e][c] = cb[c][e] ----------------
__global__ __launch_bounds__(256) void transCB(const float* __restrict__ cbk,
    float* __restrict__ cbT)
{
    __shared__ float tile[32][33];
    int c0 = blockIdx.x*32, e0 = blockIdx.y*32;
    int txx = threadIdx.x & 31, tyy = threadIdx.x >> 5;
#pragma unroll
    for (int i=0;i<4;i++)
        tile[tyy + i*8][txx] = cbk[(size_t)(c0 + tyy + i*8)*ED + e0 + txx];
    __syncthreads();
#pragma unroll
    for (int i=0;i<4;i++)
        cbT[(size_t)(e0 + tyy + i*8)*NE + c0 + txx] = tile[txx][tyy + i*8];
}

// ================= fused VQ: 128x128 dists + shuffle first-min partial argmin =================
__global__ __launch_bounds__(256, 3) void vq128(const float* __restrict__ zf,
    const float* __restrict__ cbT, const float* __restrict__ sz, const float* __restrict__ sc,
    float* __restrict__ pval, int* __restrict__ pidx)
{
    __shared__ float Zs[2][16][132];
    __shared__ float Cs[2][16][128];
    const int tid = threadIdx.x;
    const int tx = tid & 15, ty = tid >> 4;
    const int br = blockIdx.y * 128, bc = blockIdx.x * 128;
    const int ar = tid >> 1, aq = tid & 1;
    const int wv = tid >> 6, lane = tid & 63;
    const int wrow = wv*4 + (lane >> 5);
    const int wcol = (lane & 31) * 4;

    float acc[8][8];
#pragma unroll
    for (int i=0;i<8;i++)
#pragma unroll
      for (int j=0;j<8;j++) acc[i][j] = 0.0f;

    float4 ra0, ra1;
    gl2lds16(cbT + (size_t)(wrow    )*NE + bc + wcol, &Cs[0][0][0] + wv*512);
    gl2lds16(cbT + (size_t)(wrow + 2)*NE + bc + wcol, &Cs[0][0][0] + wv*512 + 256);
    {
        const float4* p = (const float4*)(zf + (size_t)(br+ar)*ED + aq*8);
        ra0 = p[0]; ra1 = p[1];
        Zs[0][aq*8+0][ar] = ra0.x; Zs[0][aq*8+1][ar] = ra0.y;
        Zs[0][aq*8+2][ar] = ra0.z; Zs[0][aq*8+3][ar] = ra0.w;
        Zs[0][aq*8+4][ar] = ra1.x; Zs[0][aq*8+5][ar] = ra1.y;
        Zs[0][aq*8+6][ar] = ra1.z; Zs[0][aq*8+7][ar] = ra1.w;
    }
    __syncthreads();

    int cur = 0;
    for (int k0 = 0; k0 < ED; k0 += 16) {
        int kn = k0 + 16;
        int nb = cur ^ 1;
        if (kn < ED) {
            gl2lds16(cbT + (size_t)(kn + wrow    )*NE + bc + wcol, &Cs[nb][0][0] + wv*512);
            gl2lds16(cbT + (size_t)(kn + wrow + 2)*NE + bc + wcol, &Cs[nb][0][0] + wv*512 + 256);
            const float4* p = (const float4*)(zf + (size_t)(br+ar)*ED + kn + aq*8);
            ra0 = p[0]; ra1 = p[1];
        }
#pragma unroll
        for (int kk = 0; kk < 16; ++kk) {
            float4 va0 = *(const float4*)&Zs[cur][kk][ty*4];
            float4 va1 = *(const float4*)&Zs[cur][kk][64 + ty*4];
            float4 vb0 = *(const float4*)&Cs[cur][kk][tx*4];
            float4 vb1 = *(const float4*)&Cs[cur][kk][64 + tx*4];
            float av[8] = {va0.x,va0.y,va0.z,va0.w, va1.x,va1.y,va1.z,va1.w};
            float bv[8] = {vb0.x,vb0.y,vb0.z,vb0.w, vb1.x,vb1.y,vb1.z,vb1.w};
#pragma unroll
            for (int i=0;i<8;i++)
#pragma unroll
                for (int j=0;j<8;j++)
                    acc[i][j] = fmaf(av[i], bv[j], acc[i][j]);
        }
        if (kn < ED) {
            Zs[nb][aq*8+0][ar] = ra0.x; Zs[nb][aq*8+1][ar] = ra0.y;
            Zs[nb][aq*8+2][ar] = ra0.z; Zs[nb][aq*8+3][ar] = ra0.w;
            Zs[nb][aq*8+4][ar] = ra1.x; Zs[nb][aq*8+5][ar] = ra1.y;
            Zs[nb][aq*8+6][ar] = ra1.z; Zs[nb][aq*8+7][ar] = ra1.w;
        }
        __syncthreads();
        cur ^= 1;
    }
    // dists + first-min: per-thread over its 8 cols, then 16-lane shuffle tree.
    // lexicographic (val, idx) min == np.argmin first-min semantics.
#pragma unroll
    for (int i=0;i<8;i++) {
        int lr = (i<4) ? ty*4+i : 64 + ty*4 + (i-4);
        float szi = sz[br + lr];
        float bvv = 0.0f; int bii = -1;
#pragma unroll
        for (int j=0;j<8;j++) {
            int lc = (j<4) ? tx*4+j : 64 + tx*4 + (j-4);
            int gc = bc + lc;
            float d = __fsub_rn(__fadd_rn(szi, sc[gc]), __fmul_rn(2.0f, acc[i][j]));
            if (bii < 0 || d < bvv || (d == bvv && gc < bii)) { bvv = d; bii = gc; }
        }
#pragma unroll
        for (int off = 8; off; off >>= 1) {
            float ov = __shfl_xor(bvv, off);
            int   oi = __shfl_xor(bii, off);
            if (ov < bvv || (ov == bvv && oi < bii)) { bvv = ov; bii = oi; }
        }
        if (tx == 0) {
            pval[(size_t)(br+lr)*16 + blockIdx.x] = bvv;
            pidx[(size_t)(br+lr)*16 + blockIdx.x] = bii;
        }
    }
}

// ================= bf16 MFMA GEMM (decoder only; loose thresholds) =================
template<int EPI>
__global__ __launch_bounds__(256) void gemm_bf16(
    const ushort* __restrict__ X, const ushort* __restrict__ WT,
    const float* __restrict__ bias, const float* __restrict__ esc,
    const float* __restrict__ esh, float* __restrict__ C,
    ushort* __restrict__ Cb, int N, int K)
{
    __shared__ ushort Xs[2][128][40];
    __shared__ ushort Ws[2][128][40];
    const int tid = threadIdx.x;
    const int lane = tid & 63, wave = tid >> 6;
    const int wr = wave >> 1, wc = wave & 1;
    const int bm = blockIdx.y * 128, bn = blockIdx.x * 128;
    const int sr = tid >> 1, sh = tid & 1;

    f32x4 acc[4][4];
#pragma unroll
    for (int m=0;m<4;m++)
#pragma unroll
      for (int n=0;n<4;n++) acc[m][n] = (f32x4){0.f,0.f,0.f,0.f};

    float4 xv0, xv1, wv0, wv1;
    {
        const float4* xp = (const float4*)(X + (size_t)(bm+sr)*K + sh*16);
        xv0 = xp[0]; xv1 = xp[1];
        const float4* wp = (const float4*)(WT + (size_t)(bn+sr)*K + sh*16);
        wv0 = wp[0]; wv1 = wp[1];
    }
    {
        float4* dx = (float4*)&Xs[0][sr][sh*16]; dx[0] = xv0; dx[1] = xv1;
        float4* dw = (float4*)&Ws[0][sr][sh*16]; dw[0] = wv0; dw[1] = wv1;
    }
    __syncthreads();

    const int ko = (lane >> 4) * 8;
    const int fr = lane & 15;
    int cur = 0;
    for (int k0 = 0; k0 < K; k0 += 32) {
        int kn = k0 + 32;
        if (kn < K) {
            const float4* xp = (const float4*)(X + (size_t)(bm+sr)*K + kn + sh*16);
            xv0 = xp[0]; xv1 = xp[1];
            const float4* wp = (const float4*)(WT + (size_t)(bn+sr)*K + kn + sh*16);
            wv0 = wp[0]; wv1 = wp[1];
        }
        bf16x8 af[4], bfr[4];
#pragma unroll
        for (int m=0;m<4;m++) af[m]  = *(const bf16x8*)&Xs[cur][wr*64 + m*16 + fr][ko];
#pragma unroll
        for (int n=0;n<4;n++) bfr[n] = *(const bf16x8*)&Ws[cur][wc*64 + n*16 + fr][ko];
#pragma unroll
        for (int m=0;m<4;m++)
#pragma unroll
            for (int n=0;n<4;n++)
                acc[m][n] = __builtin_amdgcn_mfma_f32_16x16x32_bf16(af[m], bfr[n], acc[m][n], 0, 0, 0);
        if (kn < K) {
            int nb = cur ^ 1;
            float4* dx = (float4*)&Xs[nb][sr][sh*16]; dx[0] = xv0; dx[1] = xv1;
            float4* dw = (float4*)&Ws[nb][sr][sh*16]; dw[0] = wv0; dw[1] = wv1;
        }
        __syncthreads();
        cur ^= 1;
    }
    const int cr = (lane >> 4) * 4, cc = lane & 15;
#pragma unroll
    for (int m=0;m<4;m++) {
#pragma unroll
        for (int n=0;n<4;n++) {
            int gn = bn + wc*64 + n*16 + cc;
            float bb = bias[gn];
            float s0 = 0.f, s1 = 0.f;
            if (EPI == 1) { s0 = esc[gn]; s1 = esh[gn]; }
#pragma unroll
            for (int r=0;r<4;r++) {
                int gm = bm + wr*64 + m*16 + cr + r;
                float v = acc[m][n][r] + bb;
                if (EPI == 1) v = s0*v + s1;
                size_t off = (size_t)gm*N + gn;
                C[off] = v;
                if (EPI == 2) Cb[off] = f2b(v);
            }
        }
    }
}

// ---------------- weight transpose + f32->bf16: WT[n][k] = bf16(W[k][n]) ----------------
__global__ __launch_bounds__(256) void transW(const float* __restrict__ W,
    ushort* __restrict__ WT, int K, int N)
{
    __shared__ float tile[32][33];
    int n0 = blockIdx.x*32, k0 = blockIdx.y*32;
    int tx = threadIdx.x & 31, ty8 = threadIdx.x >> 5;
#pragma unroll
    for (int i=0;i<4;i++)
        tile[ty8 + i*8][tx] = W[(size_t)(k0 + ty8 + i*8)*N + n0 + tx];
    __syncthreads();
#pragma unroll
    for (int i=0;i<4;i++) {
        int n = ty8 + i*8;
        WT[(size_t)(n0+n)*K + k0 + tx] = f2b(tile[tx][n]);
    }
}

// ---------------- LayerNorm + relu + add, numpy-f32-exact; WB=1 also writes bf16 mirror ----------------
template<int WB>
__global__ __launch_bounds__(64) void ln_np(const float* __restrict__ t,
    float* __restrict__ h, ushort* __restrict__ hb,
    const float* __restrict__ g, const float* __restrict__ be)
{
    const int row = blockIdx.x;
    const float* tr = t + (long)row*DE;
    float* hr = h + (long)row*DE;
    __shared__ float bs[16];
    __shared__ float mv[2];
    const int l = threadIdx.x;

    if (l < 16) {
        const float* p = tr + l*128;
        float r[8];
#pragma unroll
        for (int j=0;j<8;j++) r[j] = p[j];
        for (int i=8;i<128;i+=8)
#pragma unroll
            for (int j=0;j<8;j++) r[j] = __fadd_rn(r[j], p[i+j]);
        float tA = __fadd_rn(__fadd_rn(r[0],r[1]), __fadd_rn(r[2],r[3]));
        float tB = __fadd_rn(__fadd_rn(r[4],r[5]), __fadd_rn(r[6],r[7]));
        bs[l] = __fadd_rn(tA, tB);
    }
    __syncthreads();
    if (l == 0) {
        float s8[8], s4[4], s2[2];
#pragma unroll
        for (int i=0;i<8;i++) s8[i] = __fadd_rn(bs[2*i], bs[2*i+1]);
#pragma unroll
        for (int i=0;i<4;i++) s4[i] = __fadd_rn(s8[2*i], s8[2*i+1]);
#pragma unroll
        for (int i=0;i<2;i++) s2[i] = __fadd_rn(s4[2*i], s4[2*i+1]);
        mv[0] = __fdiv_rn(__fadd_rn(s2[0], s2[1]), 2048.0f);
    }
    __syncthreads();
    const float m = mv[0];
    if (l < 16) {
        const float* p = tr + l*128;
        float r[8];
#pragma unroll
        for (int j=0;j<8;j++) { float d = __fsub_rn(p[j], m); r[j] = __fmul_rn(d, d); }
        for (int i=8;i<128;i+=8)
#pragma unroll
            for (int j=0;j<8;j++) {
                float d = __fsub_rn(p[i+j], m);
                r[j] = __fadd_rn(r[j], __fmul_rn(d, d));
            }
        float tA = __fadd_rn(__fadd_rn(r[0],r[1]), __fadd_rn(r[2],r[3]));
        float tB = __fadd_rn(__fadd_rn(r[4],r[5]), __fadd_rn(r[6],r[7]));
        bs[l] = __fadd_rn(tA, tB);
    }
    __syncthreads();
    if (l == 0) {
        float s8[8], s4[4], s2[2];
#pragma unroll
        for (int i=0;i<8;i++) s8[i] = __fadd_rn(bs[2*i], bs[2*i+1]);
#pragma unroll
        for (int i=0;i<4;i++) s4[i] = __fadd_rn(s8[2*i], s8[2*i+1]);
#pragma unroll
        for (int i=0;i<2;i++) s2[i] = __fadd_rn(s4[2*i], s4[2*i+1]);
        float v = __fdiv_rn(__fadd_rn(s2[0], s2[1]), 2048.0f);
        mv[1] = __fdiv_rn(1.0f, __fsqrt_rn(__fadd_rn(v, EPSLN)));
    }
    __syncthreads();
    const float rs = mv[1];
    ushort* hbr = (WB ? hb + (long)row*DE : nullptr);
    for (int j = l; j < DE; j += 64) {
        float u = __fadd_rn(__fmul_rn(__fmul_rn(__fsub_rn(tr[j], m), rs), g[j]), be[j]);
        float r = u > 0.0f ? u : 0.0f;
        float nh = __fadd_rn(hr[j], r);
        hr[j] = nh;
        if (WB) hbr[j] = f2b(nh);
    }
}

// ---------------- IdxEmbedding, np-f32 ----------------
__global__ __launch_bounds__(128) void idx_embed_np(const int* __restrict__ bidx,
    const float* __restrict__ lay, const float* __restrict__ lty, const float* __restrict__ wty,
    const float* __restrict__ fw, const float* __restrict__ fb,
    const float* __restrict__ ow, const float* __restrict__ ob,
    float* __restrict__ oidx)
{
    const int row = blockIdx.x;
    __shared__ float emb[3*HID+3];
    __shared__ float fcv[HID];
    const int t = threadIdx.x;
    int c0 = bidx[row*6+0], c1 = bidx[row*6+1], c2 = bidx[row*6+2];
    emb[t]       = lay[c0*HID + t];
    emb[HID+t]   = lty[c1*HID + t];
    emb[2*HID+t] = wty[c2*HID + t];
    if (t < 3) emb[3*HID+t] = (float)bidx[row*6+3+t];
    __syncthreads();
    {
        float acc = 0.0f;
        for (int k = 0; k < 3*HID+3; ++k)
            acc = fmaf(emb[k], fw[k*HID + t], acc);
        fcv[t] = __fadd_rn(acc, fb[t]);
    }
    __syncthreads();
    if (t < ODIM) {
        float acc = 0.0f;
        for (int k = 0; k < HID; ++k)
            acc = fmaf(fcv[k], ow[k*ODIM + t], acc);
        oidx[(long)row*ODIM + t] = __fadd_rn(acc, ob[t]);
    }
}

// ---------------- squared row norms, numpy pairwise (4 blocks of 128) ----------------
__global__ __launch_bounds__(256) void sqnorm_np(const float* __restrict__ a, int nrows,
    float* __restrict__ outv)
{
    int rI = blockIdx.x*256 + threadIdx.x;
    if (rI >= nrows) return;
    const float* p = a + (long)rI*ED;
    float B[4];
#pragma unroll
    for (int b = 0; b < 4; ++b) {
        const float* q = p + b*128;
        float r[8];
#pragma unroll
        for (int j=0;j<8;j++) r[j] = __fmul_rn(q[j], q[j]);
        for (int i=8;i<128;i+=8)
#pragma unroll
            for (int j=0;j<8;j++) r[j] = __fadd_rn(r[j], __fmul_rn(q[i+j], q[i+j]));
        float tA = __fadd_rn(__fadd_rn(r[0],r[1]), __fadd_rn(r[2],r[3]));
        float tB = __fadd_rn(__fadd_rn(r[4],r[5]), __fadd_rn(r[6],r[7]));
        B[b] = __fadd_rn(tA, tB);
    }
    outv[rI] = __fadd_rn(__fadd_rn(B[0], B[1]), __fadd_rn(B[2], B[3]));
}

// ---------------- final argmin across 16 column blocks ----------------
__global__ __launch_bounds__(256) void vq_reduce(const float* __restrict__ pval,
    const int* __restrict__ pidx, int* __restrict__ idxw, float* __restrict__ idxf,
    int* __restrict__ cnt)
{
    int r = blockIdx.x*256 + threadIdx.x;
    const float* pv = pval + (long)r*16;
    const int*   pi = pidx + (long)r*16;
    float best = pv[0]; int bj = pi[0];
#pragma unroll
    for (int c = 1; c < 16; ++c) {
        float v = pv[c]; int ii = pi[c];
        if (v < best || (v == best && ii < bj)) { best = v; bj = ii; }
    }
    idxw[r] = bj;
    idxf[r] = (float)bj;
    atomicAdd(&cnt[bj], 1);
}

// ---------------- z_q_st + bf16 mirror + SSE accumulation ----------------
__global__ __launch_bounds__(256) void zq_loss(const int* __restrict__ idxw,
    const float* __restrict__ cbk, const float* __restrict__ z_e,
    float* __restrict__ zq_out, ushort* __restrict__ zqb, double* __restrict__ sse)
{
    double local = 0.0;
    const long total = (long)NZF*ED;
    for (long g = (long)blockIdx.x*256 + threadIdx.x; g < total; g += (long)gridDim.x*256) {
        int p = (int)(g >> 9);
        int e = (int)(g & 511);
        float q = cbk[(long)idxw[p]*ED + e];
        float z = z_e[g];
        float d = __fsub_rn(q, z);
        float o = __fadd_rn(z, d);
        zq_out[g] = o;
        zqb[g] = f2b(o);
        local += (double)d * (double)d;
    }
    for (int off = 32; off > 0; off >>= 1) local += __shfl_down(local, off);
    __shared__ double red[4];
    int wid = threadIdx.x >> 6, lane = threadIdx.x & 63;
    if (lane == 0) red[wid] = local;
    __syncthreads();
    if (threadIdx.x == 0) atomicAdd(sse, red[0]+red[1]+red[2]+red[3]);
}

// ---------------- loss + perplexity ----------------
__global__ __launch_bounds__(256) void finalize(const int* __restrict__ cnt,
    const double* __restrict__ sse, float* __restrict__ d_out)
{
    double s = 0.0;
    for (int j = threadIdx.x; j < NE; j += 256) {
        double e = (double)cnt[j] / (double)NZF;
        s += e * log(e + 1e-10);
    }
    for (int off = 32; off > 0; off >>= 1) s += __shfl_down(s, off);
    __shared__ double red[4];
    int wid = threadIdx.x >> 6, lane = threadIdx.x & 63;
    if (lane == 0) red[wid] = s;
    __syncthreads();
    if (threadIdx.x == 0) {
        double st = red[0]+red[1]+red[2]+red[3];
        d_out[0]        = (float)(1.25 * sse[0] / (double)((long)BB*DE));
        d_out[PERP_OFF] = (float)exp(-st);
    }
}

extern "C" void kernel_launch(void* const* d_in, const int* in_sizes, int n_in,
                              void* d_out_v, int out_size, void* d_ws, size_t ws_size,
                              hipStream_t stream)
{
    const float* x         = (const float*)d_in[0];
    const int*   bidx      = (const int*)  d_in[1];
    const float* scale     = (const float*)d_in[2];
    const float* shift     = (const float*)d_in[3];
    const float* enc_in_w  = (const float*)d_in[4];
    const float* enc_in_b  = (const float*)d_in[5];
    const float* enc_res_w = (const float*)d_in[6];
    const float* enc_res_b = (const float*)d_in[7];
    const float* enc_ln_g  = (const float*)d_in[8];
    const float* enc_ln_b  = (const float*)d_in[9];
    const float* lay       = (const float*)d_in[10];
    const float* lty       = (const float*)d_in[11];
    const float* wty       = (const float*)d_in[12];
    const float* fcw       = (const float*)d_in[13];
    const float* fcb       = (const float*)d_in[14];
    const float* oww       = (const float*)d_in[15];
    const float* owb       = (const float*)d_in[16];
    const float* catw      = (const float*)d_in[17];
    const float* catb      = (const float*)d_in[18];
    const float* cbk       = (const float*)d_in[19];
    const float* dec_in_w  = (const float*)d_in[20];
    const float* dec_in_b  = (const float*)d_in[21];
    const float* dec_res_w = (const float*)d_in[22];
    const float* dec_res_b = (const float*)d_in[23];
    const float* dec_ln_g  = (const float*)d_in[24];
    const float* dec_ln_b  = (const float*)d_in[25];
    const float* dec_out_w = (const float*)d_in[26];
    const float* dec_out_b = (const float*)d_in[27];
    float* out = (float*)d_out_v;

    char* w = (char*)d_ws;
    auto alloc = [&](size_t bytes) {
        char* p = w;
        w += (bytes + 255) & ~(size_t)255;
        return p;
    };
    float*  xs   = (float*)alloc((size_t)BB*INW*4);     // dead after enc_in GEMM
    float*  h    = (float*)alloc((size_t)BB*DE*4);
    float*  t    = (float*)alloc((size_t)BB*DE*4);
    float*  oidx = (float*)alloc((size_t)BB*ODIM*4);
    int*    idxw = (int*)  alloc((size_t)NZF*4);
    float*  szv  = (float*)alloc((size_t)NZF*4);
    float*  scv  = (float*)alloc((size_t)NE*4);
    int*    cnt  = (int*)  alloc((size_t)NE*4);
    double* sse  = (double*)alloc(8);
    float*  cbT  = (float*)alloc((size_t)ED*NE*4);      // 4MB transposed codebook
    ushort* zqb  = (ushort*)alloc((size_t)BB*DE*2);     // bf16 z_q_st
    ushort* hb   = (ushort*)alloc((size_t)BB*DE*2);     // bf16 decoder hidden
    ushort* wt1  = (ushort*)alloc((size_t)DE*DE*2);     // dec_in_w^T bf16
    ushort* wt2  = (ushort*)alloc((size_t)DE*DE*2);     // dec_res_w^T bf16
    ushort* wt3  = (ushort*)alloc((size_t)INW*DE*2);    // dec_out_w^T bf16
    // aliases:
    float*  z_e  = t;
    float*  pval = (float*)xs;                          // NZF*16*4 (xs dead)
    int*    pidx = (int*)(xs + (size_t)NZF*16);

    hipMemsetAsync(cnt, 0, (size_t)NE*4, stream);
    hipMemsetAsync(sse, 0, 8, stream);

    dim3 gDE(DE/128, BB/128);    // (16,64)
    dim3 gIN(INW/128, BB/128);   // (8,64)
    dim3 gVQ(NE/128, NZF/128);   // (16,256)

    // ---- encoder: numpy-f32-exact semantics ----
    prep_xs<<<2048, 256, 0, stream>>>(x, scale, shift, xs);
    gemm_f32<0><<<gDE, 256, 0, stream>>>(xs, INW, nullptr, 0, enc_in_w, enc_in_b, h, DE);
    for (int r = 0; r < NRES; ++r) {
        gemm_f32<0><<<gDE, 256, 0, stream>>>(h, DE, nullptr, 0, enc_res_w, enc_res_b, t, DE);
        ln_np<0><<<BB, 64, 0, stream>>>(t, h, nullptr, enc_ln_g, enc_ln_b);
    }
    idx_embed_np<<<BB, 128, 0, stream>>>(bidx, lay, lty, wty, fcw, fcb, oww, owb, oidx);
    gemm_f32<1><<<gDE, 256, 0, stream>>>(h, DE, oidx, ODIM, catw, catb, z_e, DE);
    // ---- VQ: numpy-f32 dists + first-min argmin ----
    transCB<<<dim3(NE/32, ED/32), 256, 0, stream>>>(cbk, cbT);
    sqnorm_np<<<NZF/256, 256, 0, stream>>>(z_e, NZF, szv);
    sqnorm_np<<<NE/256, 256, 0, stream>>>(cbk, NE, scv);
    vq128<<<gVQ, 256, 0, stream>>>(z_e, cbT, szv, scv, pval, pidx);
    vq_reduce<<<NZF/256, 256, 0, stream>>>(pval, pidx, idxw, out + IDX_OFF, cnt);
    zq_loss<<<2048, 256, 0, stream>>>(idxw, cbk, z_e, out + ZQ_OFF, zqb, sse);
    finalize<<<1, 256, 0, stream>>>(cnt, sse, out);
    // ---- decoder: bf16 MFMA (loose thresholds) ----
    transW<<<dim3(DE/32, DE/32), 256, 0, stream>>>(dec_in_w,  wt1, DE, DE);
    transW<<<dim3(DE/32, DE/32), 256, 0, stream>>>(dec_res_w, wt2, DE, DE);
    transW<<<dim3(INW/32, DE/32), 256, 0, stream>>>(dec_out_w, wt3, DE, INW);
    gemm_bf16<2><<<gDE, 256, 0, stream>>>(zqb, wt1, dec_in_b, nullptr, nullptr, h, hb, DE, DE);
    for (int r = 0; r < NRES; ++r) {
        gemm_bf16<0><<<gDE, 256, 0, stream>>>(hb, wt2, dec_res_b, nullptr, nullptr, t, nullptr, DE, DE);
        ln_np<1><<<BB, 64, 0, stream>>>(t, h, hb, dec_ln_g, dec_ln_b);
    }
    gemm_bf16<1><<<gIN, 256, 0, stream>>>(hb, wt3, dec_out_b, scale, shift, out + XHAT_OFF, nullptr, INW, DE);
}

// Round 8
// 12683.610 us; speedup vs baseline: 6.6306x; 4.3664x over previous
//
#include <hip/hip_runtime.h>
#include <math.h>

#define BB 8192
#define INW 1024
#define DE 2048
#define NRES 4
#define NE 2048
#define ED 512
#define HID 128
#define ODIM 64
#define NZF (BB*4)
#define EPSLN 1e-5f

// d_out layout: loss, x_hat(B*IN), perplexity, z_q_st(B*DE), idx(NZF)
#define XHAT_OFF 1
#define PERP_OFF (1 + BB*INW)
#define ZQ_OFF   (PERP_OFF + 1)
#define IDX_OFF  (ZQ_OFF + BB*DE)

typedef short bf16x8 __attribute__((ext_vector_type(8)));
typedef float f32x4 __attribute__((ext_vector_type(4)));

__device__ __forceinline__ ushort f2b(float f) {
    unsigned u = __float_as_uint(f);
    unsigned r = (u + 0x7FFFu + ((u >> 16) & 1u)) >> 16;
    return (ushort)r;
}

// async global->LDS, 16B per lane; lds base must be wave-uniform (HW adds lane*16)
__device__ __forceinline__ void gl2lds16(const void* g, void* l) {
    __builtin_amdgcn_global_load_lds(
        (__attribute__((address_space(1))) void*)(g),
        (__attribute__((address_space(3))) void*)(l), 16, 0, 0);
}

// ---------------- prep: xs = (x - shift) / scale (np f32 semantics) ----------------
__global__ __launch_bounds__(256) void prep_xs(const float* __restrict__ x,
    const float* __restrict__ scale, const float* __restrict__ shift,
    float* __restrict__ xs)
{
    const long total = (long)BB*INW;
    for (long g = (long)blockIdx.x*256 + threadIdx.x; g < total; g += (long)gridDim.x*256) {
        int k = (int)(g & (INW-1));
        xs[g] = __fdiv_rn(__fsub_rn(x[g], shift[k]), scale[k]);
    }
}

// ================= fast f32 GEMM, np/BLAS-exact per-element FMA chain =================
// C[m][n] = (sum_k ascending, single fmaf chain) + bias[n].  128x128 tile, 8x8 micro.
// W staged via global_load_lds into unpadded [16][128]; A reg-staged transposed.
// amdgpu_num_vgpr(160): direct VGPR cap -> 3 waves/SIMD on the 512-reg file.
// (launch_bounds waves-arg computes its budget from a 256-reg table: (256,4)->64,
//  (256,3)->84 VGPRs, both spill the 64-reg accumulator -- measured rounds 6/7.)
template<int HASA2>
__global__ __launch_bounds__(256) __attribute__((amdgpu_num_vgpr(160)))
void gemm_f32(
    const float* __restrict__ A1, int K1, const float* __restrict__ A2, int K2,
    const float* __restrict__ W, const float* __restrict__ bias,
    float* __restrict__ C, int N)
{
    __shared__ float As[2][16][132];
    __shared__ float Ws[2][16][128];
    const int tid = threadIdx.x;
    const int tx = tid & 15, ty = tid >> 4;
    const int bm = blockIdx.y * 128, bn = blockIdx.x * 128;
    const int K = K1 + K2;
    const int ar = tid >> 1, aq = tid & 1;          // A staging: row, k-half
    const int wv = tid >> 6, lane = tid & 63;       // W staging via lds-DMA
    const int wrow = wv*4 + (lane >> 5);            // tile k-row (+2 for q=1)
    const int wcol = (lane & 31) * 4;               // tile col

    float acc[8][8];
#pragma unroll
    for (int i=0;i<8;i++)
#pragma unroll
      for (int j=0;j<8;j++) acc[i][j] = 0.0f;

    float4 ra0, ra1;
    // prologue: stage tile 0
    gl2lds16(W + (size_t)(wrow    )*N + bn + wcol, &Ws[0][0][0] + wv*512);
    gl2lds16(W + (size_t)(wrow + 2)*N + bn + wcol, &Ws[0][0][0] + wv*512 + 256);
    {
        const float4* p = (const float4*)(A1 + (size_t)(bm+ar)*K1 + aq*8);
        ra0 = p[0]; ra1 = p[1];
        As[0][aq*8+0][ar] = ra0.x; As[0][aq*8+1][ar] = ra0.y;
        As[0][aq*8+2][ar] = ra0.z; As[0][aq*8+3][ar] = ra0.w;
        As[0][aq*8+4][ar] = ra1.x; As[0][aq*8+5][ar] = ra1.y;
        As[0][aq*8+6][ar] = ra1.z; As[0][aq*8+7][ar] = ra1.w;
    }
    __syncthreads();

    int cur = 0;
    for (int k0 = 0; k0 < K; k0 += 16) {
        int kn = k0 + 16;
        int nb = cur ^ 1;
        if (kn < K) {
            // W -> LDS DMA (async, lands before next barrier)
            gl2lds16(W + (size_t)(kn + wrow    )*N + bn + wcol, &Ws[nb][0][0] + wv*512);
            gl2lds16(W + (size_t)(kn + wrow + 2)*N + bn + wcol, &Ws[nb][0][0] + wv*512 + 256);
            // A -> regs
            const float* s;
            if (HASA2 && kn >= K1) s = A2 + (size_t)(bm+ar)*K2 + (kn - K1) + aq*8;
            else                   s = A1 + (size_t)(bm+ar)*K1 + kn + aq*8;
            const float4* p = (const float4*)s;
            ra0 = p[0]; ra1 = p[1];
        }
#pragma unroll
        for (int kk = 0; kk < 16; ++kk) {
            float4 va0 = *(const float4*)&As[cur][kk][ty*4];
            float4 va1 = *(const float4*)&As[cur][kk][64 + ty*4];
            float4 vb0 = *(const float4*)&Ws[cur][kk][tx*4];
            float4 vb1 = *(const float4*)&Ws[cur][kk][64 + tx*4];
            float av[8] = {va0.x,va0.y,va0.z,va0.w, va1.x,va1.y,va1.z,va1.w};
            float bv[8] = {vb0.x,vb0.y,vb0.z,vb0.w, vb1.x,vb1.y,vb1.z,vb1.w};
#pragma unroll
            for (int i=0;i<8;i++)
#pragma unroll
                for (int j=0;j<8;j++)
                    acc[i][j] = fmaf(av[i], bv[j], acc[i][j]);
        }
        if (kn < K) {
            As[nb][aq*8+0][ar] = ra0.x; As[nb][aq*8+1][ar] = ra0.y;
            As[nb][aq*8+2][ar] = ra0.z; As[nb][aq*8+3][ar] = ra0.w;
            As[nb][aq*8+4][ar] = ra1.x; As[nb][aq*8+5][ar] = ra1.y;
            As[nb][aq*8+6][ar] = ra1.z; As[nb][aq*8+7][ar] = ra1.w;
        }
        __syncthreads();
        cur ^= 1;
    }
    // epilogue
    float4 bv0 = *(const float4*)&bias[bn + tx*4];
    float4 bv1 = *(const float4*)&bias[bn + 64 + tx*4];
    const float bb[8] = {bv0.x,bv0.y,bv0.z,bv0.w, bv1.x,bv1.y,bv1.z,bv1.w};
#pragma unroll
    for (int i=0;i<8;i++) {
        int gm = bm + ((i<4) ? ty*4+i : 64 + ty*4 + (i-4));
        float4 o0, o1;
        o0.x = __fadd_rn(acc[i][0], bb[0]); o0.y = __fadd_rn(acc[i][1], bb[1]);
        o0.z = __fadd_rn(acc[i][2], bb[2]); o0.w = __fadd_rn(acc[i][3], bb[3]);
        o1.x = __fadd_rn(acc[i][4], bb[4]); o1.y = __fadd_rn(acc[i][5], bb[5]);
        o1.z = __fadd_rn(acc[i][6], bb[6]); o1.w = __fadd_rn(acc[i][7], bb[7]);
        *(float4*)&C[(size_t)gm*N + bn + tx*4]      = o0;
        *(float4*)&C[(size_t)gm*N + bn + 64 + tx*4] = o1;
    }
}

// ---------------- codebook transpose (exact copy): cbT[e][c] = cb[c][e] ----------------
__global__ __launch_bounds__(256) void transCB(const float* __restrict__ cbk,
    float* __restrict__ cbT)
{
    __shared__ float tile[32][33];
    int c0 = blockIdx.x*32, e0 = blockIdx.y*32;
    int txx = threadIdx.x & 31, tyy = threadIdx.x >> 5;
#pragma unroll
    for (int i=0;i<4;i++)
        tile[tyy + i*8][txx] = cbk[(size_t)(c0 + tyy + i*8)*ED + e0 + txx];
    __syncthreads();
#pragma unroll
    for (int i=0;i<4;i++)
        cbT[(size_t)(e0 + tyy + i*8)*NE + c0 + txx] = tile[txx][tyy + i*8];
}

// ================= fused VQ: 128x128 dists + shuffle first-min partial argmin =================
__global__ __launch_bounds__(256) __attribute__((amdgpu_num_vgpr(160)))
void vq128(const float* __restrict__ zf,
    const float* __restrict__ cbT, const float* __restrict__ sz, const float* __restrict__ sc,
    float* __restrict__ pval, int* __restrict__ pidx)
{
    __shared__ float Zs[2][16][132];
    __shared__ float Cs[2][16][128];
    const int tid = threadIdx.x;
    const int tx = tid & 15, ty = tid >> 4;
    const int br = blockIdx.y * 128, bc = blockIdx.x * 128;
    const int ar = tid >> 1, aq = tid & 1;
    const int wv = tid >> 6, lane = tid & 63;
    const int wrow = wv*4 + (lane >> 5);
    const int wcol = (lane & 31) * 4;

    float acc[8][8];
#pragma unroll
    for (int i=0;i<8;i++)
#pragma unroll
      for (int j=0;j<8;j++) acc[i][j] = 0.0f;

    float4 ra0, ra1;
    gl2lds16(cbT + (size_t)(wrow    )*NE + bc + wcol, &Cs[0][0][0] + wv*512);
    gl2lds16(cbT + (size_t)(wrow + 2)*NE + bc + wcol, &Cs[0][0][0] + wv*512 + 256);
    {
        const float4* p = (const float4*)(zf + (size_t)(br+ar)*ED + aq*8);
        ra0 = p[0]; ra1 = p[1];
        Zs[0][aq*8+0][ar] = ra0.x; Zs[0][aq*8+1][ar] = ra0.y;
        Zs[0][aq*8+2][ar] = ra0.z; Zs[0][aq*8+3][ar] = ra0.w;
        Zs[0][aq*8+4][ar] = ra1.x; Zs[0][aq*8+5][ar] = ra1.y;
        Zs[0][aq*8+6][ar] = ra1.z; Zs[0][aq*8+7][ar] = ra1.w;
    }
    __syncthreads();

    int cur = 0;
    for (int k0 = 0; k0 < ED; k0 += 16) {
        int kn = k0 + 16;
        int nb = cur ^ 1;
        if (kn < ED) {
            gl2lds16(cbT + (size_t)(kn + wrow    )*NE + bc + wcol, &Cs[nb][0][0] + wv*512);
            gl2lds16(cbT + (size_t)(kn + wrow + 2)*NE + bc + wcol, &Cs[nb][0][0] + wv*512 + 256);
            const float4* p = (const float4*)(zf + (size_t)(br+ar)*ED + kn + aq*8);
            ra0 = p[0]; ra1 = p[1];
        }
#pragma unroll
        for (int kk = 0; kk < 16; ++kk) {
            float4 va0 = *(const float4*)&Zs[cur][kk][ty*4];
            float4 va1 = *(const float4*)&Zs[cur][kk][64 + ty*4];
            float4 vb0 = *(const float4*)&Cs[cur][kk][tx*4];
            float4 vb1 = *(const float4*)&Cs[cur][kk][64 + tx*4];
            float av[8] = {va0.x,va0.y,va0.z,va0.w, va1.x,va1.y,va1.z,va1.w};
            float bv[8] = {vb0.x,vb0.y,vb0.z,vb0.w, vb1.x,vb1.y,vb1.z,vb1.w};
#pragma unroll
            for (int i=0;i<8;i++)
#pragma unroll
                for (int j=0;j<8;j++)
                    acc[i][j] = fmaf(av[i], bv[j], acc[i][j]);
        }
        if (kn < ED) {
            Zs[nb][aq*8+0][ar] = ra0.x; Zs[nb][aq*8+1][ar] = ra0.y;
            Zs[nb][aq*8+2][ar] = ra0.z; Zs[nb][aq*8+3][ar] = ra0.w;
            Zs[nb][aq*8+4][ar] = ra1.x; Zs[nb][aq*8+5][ar] = ra1.y;
            Zs[nb][aq*8+6][ar] = ra1.z; Zs[nb][aq*8+7][ar] = ra1.w;
        }
        __syncthreads();
        cur ^= 1;
    }
    // dists + first-min: per-thread over its 8 cols, then 16-lane shuffle tree.
    // lexicographic (val, idx) min == np.argmin first-min semantics.
#pragma unroll
    for (int i=0;i<8;i++) {
        int lr = (i<4) ? ty*4+i : 64 + ty*4 + (i-4);
        float szi = sz[br + lr];
        float bvv = 0.0f; int bii = -1;
#pragma unroll
        for (int j=0;j<8;j++) {
            int lc = (j<4) ? tx*4+j : 64 + tx*4 + (j-4);
            int gc = bc + lc;
            float d = __fsub_rn(__fadd_rn(szi, sc[gc]), __fmul_rn(2.0f, acc[i][j]));
            if (bii < 0 || d < bvv || (d == bvv && gc < bii)) { bvv = d; bii = gc; }
        }
#pragma unroll
        for (int off = 8; off; off >>= 1) {
            float ov = __shfl_xor(bvv, off);
            int   oi = __shfl_xor(bii, off);
            if (ov < bvv || (ov == bvv && oi < bii)) { bvv = ov; bii = oi; }
        }
        if (tx == 0) {
            pval[(size_t)(br+lr)*16 + blockIdx.x] = bvv;
            pidx[(size_t)(br+lr)*16 + blockIdx.x] = bii;
        }
    }
}

// ================= bf16 MFMA GEMM (decoder only; loose thresholds) =================
template<int EPI>
__global__ __launch_bounds__(256) void gemm_bf16(
    const ushort* __restrict__ X, const ushort* __restrict__ WT,
    const float* __restrict__ bias, const float* __restrict__ esc,
    const float* __restrict__ esh, float* __restrict__ C,
    ushort* __restrict__ Cb, int N, int K)
{
    __shared__ ushort Xs[2][128][40];
    __shared__ ushort Ws[2][128][40];
    const int tid = threadIdx.x;
    const int lane = tid & 63, wave = tid >> 6;
    const int wr = wave >> 1, wc = wave & 1;
    const int bm = blockIdx.y * 128, bn = blockIdx.x * 128;
    const int sr = tid >> 1, sh = tid & 1;

    f32x4 acc[4][4];
#pragma unroll
    for (int m=0;m<4;m++)
#pragma unroll
      for (int n=0;n<4;n++) acc[m][n] = (f32x4){0.f,0.f,0.f,0.f};

    float4 xv0, xv1, wv0, wv1;
    {
        const float4* xp = (const float4*)(X + (size_t)(bm+sr)*K + sh*16);
        xv0 = xp[0]; xv1 = xp[1];
        const float4* wp = (const float4*)(WT + (size_t)(bn+sr)*K + sh*16);
        wv0 = wp[0]; wv1 = wp[1];
    }
    {
        float4* dx = (float4*)&Xs[0][sr][sh*16]; dx[0] = xv0; dx[1] = xv1;
        float4* dw = (float4*)&Ws[0][sr][sh*16]; dw[0] = wv0; dw[1] = wv1;
    }
    __syncthreads();

    const int ko = (lane >> 4) * 8;
    const int fr = lane & 15;
    int cur = 0;
    for (int k0 = 0; k0 < K; k0 += 32) {
        int kn = k0 + 32;
        if (kn < K) {
            const float4* xp = (const float4*)(X + (size_t)(bm+sr)*K + kn + sh*16);
            xv0 = xp[0]; xv1 = xp[1];
            const float4* wp = (const float4*)(WT + (size_t)(bn+sr)*K + kn + sh*16);
            wv0 = wp[0]; wv1 = wp[1];
        }
        bf16x8 af[4], bfr[4];
#pragma unroll
        for (int m=0;m<4;m++) af[m]  = *(const bf16x8*)&Xs[cur][wr*64 + m*16 + fr][ko];
#pragma unroll
        for (int n=0;n<4;n++) bfr[n] = *(const bf16x8*)&Ws[cur][wc*64 + n*16 + fr][ko];
#pragma unroll
        for (int m=0;m<4;m++)
#pragma unroll
            for (int n=0;n<4;n++)
                acc[m][n] = __builtin_amdgcn_mfma_f32_16x16x32_bf16(af[m], bfr[n], acc[m][n], 0, 0, 0);
        if (kn < K) {
            int nb = cur ^ 1;
            float4* dx = (float4*)&Xs[nb][sr][sh*16]; dx[0] = xv0; dx[1] = xv1;
            float4* dw = (float4*)&Ws[nb][sr][sh*16]; dw[0] = wv0; dw[1] = wv1;
        }
        __syncthreads();
        cur ^= 1;
    }
    const int cr = (lane >> 4) * 4, cc = lane & 15;
#pragma unroll
    for (int m=0;m<4;m++) {
#pragma unroll
        for (int n=0;n<4;n++) {
            int gn = bn + wc*64 + n*16 + cc;
            float bb = bias[gn];
            float s0 = 0.f, s1 = 0.f;
            if (EPI == 1) { s0 = esc[gn]; s1 = esh[gn]; }
#pragma unroll
            for (int r=0;r<4;r++) {
                int gm = bm + wr*64 + m*16 + cr + r;
                float v = acc[m][n][r] + bb;
                if (EPI == 1) v = s0*v + s1;
                size_t off = (size_t)gm*N + gn;
                C[off] = v;
                if (EPI == 2) Cb[off] = f2b(v);
            }
        }
    }
}

// ---------------- weight transpose + f32->bf16: WT[n][k] = bf16(W[k][n]) ----------------
__global__ __launch_bounds__(256) void transW(const float* __restrict__ W,
    ushort* __restrict__ WT, int K, int N)
{
    __shared__ float tile[32][33];
    int n0 = blockIdx.x*32, k0 = blockIdx.y*32;
    int tx = threadIdx.x & 31, ty8 = threadIdx.x >> 5;
#pragma unroll
    for (int i=0;i<4;i++)
        tile[ty8 + i*8][tx] = W[(size_t)(k0 + ty8 + i*8)*N + n0 + tx];
    __syncthreads();
#pragma unroll
    for (int i=0;i<4;i++) {
        int n = ty8 + i*8;
        WT[(size_t)(n0+n)*K + k0 + tx] = f2b(tile[tx][n]);
    }
}

// ---------------- LayerNorm + relu + add, numpy-f32-exact; WB=1 also writes bf16 mirror ----------------
template<int WB>
__global__ __launch_bounds__(64) void ln_np(const float* __restrict__ t,
    float* __restrict__ h, ushort* __restrict__ hb,
    const float* __restrict__ g, const float* __restrict__ be)
{
    const int row = blockIdx.x;
    const float* tr = t + (long)row*DE;
    float* hr = h + (long)row*DE;
    __shared__ float bs[16];
    __shared__ float mv[2];
    const int l = threadIdx.x;

    if (l < 16) {
        const float* p = tr + l*128;
        float r[8];
#pragma unroll
        for (int j=0;j<8;j++) r[j] = p[j];
        for (int i=8;i<128;i+=8)
#pragma unroll
            for (int j=0;j<8;j++) r[j] = __fadd_rn(r[j], p[i+j]);
        float tA = __fadd_rn(__fadd_rn(r[0],r[1]), __fadd_rn(r[2],r[3]));
        float tB = __fadd_rn(__fadd_rn(r[4],r[5]), __fadd_rn(r[6],r[7]));
        bs[l] = __fadd_rn(tA, tB);
    }
    __syncthreads();
    if (l == 0) {
        float s8[8], s4[4], s2[2];
#pragma unroll
        for (int i=0;i<8;i++) s8[i] = __fadd_rn(bs[2*i], bs[2*i+1]);
#pragma unroll
        for (int i=0;i<4;i++) s4[i] = __fadd_rn(s8[2*i], s8[2*i+1]);
#pragma unroll
        for (int i=0;i<2;i++) s2[i] = __fadd_rn(s4[2*i], s4[2*i+1]);
        mv[0] = __fdiv_rn(__fadd_rn(s2[0], s2[1]), 2048.0f);
    }
    __syncthreads();
    const float m = mv[0];
    if (l < 16) {
        const float* p = tr + l*128;
        float r[8];
#pragma unroll
        for (int j=0;j<8;j++) { float d = __fsub_rn(p[j], m); r[j] = __fmul_rn(d, d); }
        for (int i=8;i<128;i+=8)
#pragma unroll
            for (int j=0;j<8;j++) {
                float d = __fsub_rn(p[i+j], m);
                r[j] = __fadd_rn(r[j], __fmul_rn(d, d));
            }
        float tA = __fadd_rn(__fadd_rn(r[0],r[1]), __fadd_rn(r[2],r[3]));
        float tB = __fadd_rn(__fadd_rn(r[4],r[5]), __fadd_rn(r[6],r[7]));
        bs[l] = __fadd_rn(tA, tB);
    }
    __syncthreads();
    if (l == 0) {
        float s8[8], s4[4], s2[2];
#pragma unroll
        for (int i=0;i<8;i++) s8[i] = __fadd_rn(bs[2*i], bs[2*i+1]);
#pragma unroll
        for (int i=0;i<4;i++) s4[i] = __fadd_rn(s8[2*i], s8[2*i+1]);
#pragma unroll
        for (int i=0;i<2;i++) s2[i] = __fadd_rn(s4[2*i], s4[2*i+1]);
        float v = __fdiv_rn(__fadd_rn(s2[0], s2[1]), 2048.0f);
        mv[1] = __fdiv_rn(1.0f, __fsqrt_rn(__fadd_rn(v, EPSLN)));
    }
    __syncthreads();
    const float rs = mv[1];
    ushort* hbr = (WB ? hb + (long)row*DE : nullptr);
    for (int j = l; j < DE; j += 64) {
        float u = __fadd_rn(__fmul_rn(__fmul_rn(__fsub_rn(tr[j], m), rs), g[j]), be[j]);
        float r = u > 0.0f ? u : 0.0f;
        float nh = __fadd_rn(hr[j], r);
        hr[j] = nh;
        if (WB) hbr[j] = f2b(nh);
    }
}

// ---------------- IdxEmbedding, np-f32 ----------------
__global__ __launch_bounds__(128) void idx_embed_np(const int* __restrict__ bidx,
    const float* __restrict__ lay, const float* __restrict__ lty, const float* __restrict__ wty,
    const float* __restrict__ fw, const float* __restrict__ fb,
    const float* __restrict__ ow, const float* __restrict__ ob,
    float* __restrict__ oidx)
{
    const int row = blockIdx.x;
    __shared__ float emb[3*HID+3];
    __shared__ float fcv[HID];
    const int t = threadIdx.x;
    int c0 = bidx[row*6+0], c1 = bidx[row*6+1], c2 = bidx[row*6+2];
    emb[t]       = lay[c0*HID + t];
    emb[HID+t]   = lty[c1*HID + t];
    emb[2*HID+t] = wty[c2*HID + t];
    if (t < 3) emb[3*HID+t] = (float)bidx[row*6+3+t];
    __syncthreads();
    {
        float acc = 0.0f;
        for (int k = 0; k < 3*HID+3; ++k)
            acc = fmaf(emb[k], fw[k*HID + t], acc);
        fcv[t] = __fadd_rn(acc, fb[t]);
    }
    __syncthreads();
    if (t < ODIM) {
        float acc = 0.0f;
        for (int k = 0; k < HID; ++k)
            acc = fmaf(fcv[k], ow[k*ODIM + t], acc);
        oidx[(long)row*ODIM + t] = __fadd_rn(acc, ob[t]);
    }
}

// ---------------- squared row norms, numpy pairwise (4 blocks of 128) ----------------
__global__ __launch_bounds__(256) void sqnorm_np(const float* __restrict__ a, int nrows,
    float* __restrict__ outv)
{
    int rI = blockIdx.x*256 + threadIdx.x;
    if (rI >= nrows) return;
    const float* p = a + (long)rI*ED;
    float B[4];
#pragma unroll
    for (int b = 0; b < 4; ++b) {
        const float* q = p + b*128;
        float r[8];
#pragma unroll
        for (int j=0;j<8;j++) r[j] = __fmul_rn(q[j], q[j]);
        for (int i=8;i<128;i+=8)
#pragma unroll
            for (int j=0;j<8;j++) r[j] = __fadd_rn(r[j], __fmul_rn(q[i+j], q[i+j]));
        float tA = __fadd_rn(__fadd_rn(r[0],r[1]), __fadd_rn(r[2],r[3]));
        float tB = __fadd_rn(__fadd_rn(r[4],r[5]), __fadd_rn(r[6],r[7]));
        B[b] = __fadd_rn(tA, tB);
    }
    outv[rI] = __fadd_rn(__fadd_rn(B[0], B[1]), __fadd_rn(B[2], B[3]));
}

// ---------------- final argmin across 16 column blocks ----------------
__global__ __launch_bounds__(256) void vq_reduce(const float* __restrict__ pval,
    const int* __restrict__ pidx, int* __restrict__ idxw, float* __restrict__ idxf,
    int* __restrict__ cnt)
{
    int r = blockIdx.x*256 + threadIdx.x;
    const float* pv = pval + (long)r*16;
    const int*   pi = pidx + (long)r*16;
    float best = pv[0]; int bj = pi[0];
#pragma unroll
    for (int c = 1; c < 16; ++c) {
        float v = pv[c]; int ii = pi[c];
        if (v < best || (v == best && ii < bj)) { best = v; bj = ii; }
    }
    idxw[r] = bj;
    idxf[r] = (float)bj;
    atomicAdd(&cnt[bj], 1);
}

// ---------------- z_q_st + bf16 mirror + SSE accumulation ----------------
__global__ __launch_bounds__(256) void zq_loss(const int* __restrict__ idxw,
    const float* __restrict__ cbk, const float* __restrict__ z_e,
    float* __restrict__ zq_out, ushort* __restrict__ zqb, double* __restrict__ sse)
{
    double local = 0.0;
    const long total = (long)NZF*ED;
    for (long g = (long)blockIdx.x*256 + threadIdx.x; g < total; g += (long)gridDim.x*256) {
        int p = (int)(g >> 9);
        int e = (int)(g & 511);
        float q = cbk[(long)idxw[p]*ED + e];
        float z = z_e[g];
        float d = __fsub_rn(q, z);
        float o = __fadd_rn(z, d);
        zq_out[g] = o;
        zqb[g] = f2b(o);
        local += (double)d * (double)d;
    }
    for (int off = 32; off > 0; off >>= 1) local += __shfl_down(local, off);
    __shared__ double red[4];
    int wid = threadIdx.x >> 6, lane = threadIdx.x & 63;
    if (lane == 0) red[wid] = local;
    __syncthreads();
    if (threadIdx.x == 0) atomicAdd(sse, red[0]+red[1]+red[2]+red[3]);
}

// ---------------- loss + perplexity ----------------
__global__ __launch_bounds__(256) void finalize(const int* __restrict__ cnt,
    const double* __restrict__ sse, float* __restrict__ d_out)
{
    double s = 0.0;
    for (int j = threadIdx.x; j < NE; j += 256) {
        double e = (double)cnt[j] / (double)NZF;
        s += e * log(e + 1e-10);
    }
    for (int off = 32; off > 0; off >>= 1) s += __shfl_down(s, off);
    __shared__ double red[4];
    int wid = threadIdx.x >> 6, lane = threadIdx.x & 63;
    if (lane == 0) red[wid] = s;
    __syncthreads();
    if (threadIdx.x == 0) {
        double st = red[0]+red[1]+red[2]+red[3];
        d_out[0]        = (float)(1.25 * sse[0] / (double)((long)BB*DE));
        d_out[PERP_OFF] = (float)exp(-st);
    }
}

extern "C" void kernel_launch(void* const* d_in, const int* in_sizes, int n_in,
                              void* d_out_v, int out_size, void* d_ws, size_t ws_size,
                              hipStream_t stream)
{
    const float* x         = (const float*)d_in[0];
    const int*   bidx      = (const int*)  d_in[1];
    const float* scale     = (const float*)d_in[2];
    const float* shift     = (const float*)d_in[3];
    const float* enc_in_w  = (const float*)d_in[4];
    const float* enc_in_b  = (const float*)d_in[5];
    const float* enc_res_w = (const float*)d_in[6];
    const float* enc_res_b = (const float*)d_in[7];
    const float* enc_ln_g  = (const float*)d_in[8];
    const float* enc_ln_b  = (const float*)d_in[9];
    const float* lay       = (const float*)d_in[10];
    const float* lty       = (const float*)d_in[11];
    const float* wty       = (const float*)d_in[12];
    const float* fcw       = (const float*)d_in[13];
    const float* fcb       = (const float*)d_in[14];
    const float* oww       = (const float*)d_in[15];
    const float* owb       = (const float*)d_in[16];
    const float* catw      = (const float*)d_in[17];
    const float* catb      = (const float*)d_in[18];
    const float* cbk       = (const float*)d_in[19];
    const float* dec_in_w  = (const float*)d_in[20];
    const float* dec_in_b  = (const float*)d_in[21];
    const float* dec_res_w = (const float*)d_in[22];
    const float* dec_res_b = (const float*)d_in[23];
    const float* dec_ln_g  = (const float*)d_in[24];
    const float* dec_ln_b  = (const float*)d_in[25];
    const float* dec_out_w = (const float*)d_in[26];
    const float* dec_out_b = (const float*)d_in[27];
    float* out = (float*)d_out_v;

    char* w = (char*)d_ws;
    auto alloc = [&](size_t bytes) {
        char* p = w;
        w += (bytes + 255) & ~(size_t)255;
        return p;
    };
    float*  xs   = (float*)alloc((size_t)BB*INW*4);     // dead after enc_in GEMM
    float*  h    = (float*)alloc((size_t)BB*DE*4);
    float*  t    = (float*)alloc((size_t)BB*DE*4);
    float*  oidx = (float*)alloc((size_t)BB*ODIM*4);
    int*    idxw = (int*)  alloc((size_t)NZF*4);
    float*  szv  = (float*)alloc((size_t)NZF*4);
    float*  scv  = (float*)alloc((size_t)NE*4);
    int*    cnt  = (int*)  alloc((size_t)NE*4);
    double* sse  = (double*)alloc(8);
    float*  cbT  = (float*)alloc((size_t)ED*NE*4);      // 4MB transposed codebook
    ushort* zqb  = (ushort*)alloc((size_t)BB*DE*2);     // bf16 z_q_st
    ushort* hb   = (ushort*)alloc((size_t)BB*DE*2);     // bf16 decoder hidden
    ushort* wt1  = (ushort*)alloc((size_t)DE*DE*2);     // dec_in_w^T bf16
    ushort* wt2  = (ushort*)alloc((size_t)DE*DE*2);     // dec_res_w^T bf16
    ushort* wt3  = (ushort*)alloc((size_t)INW*DE*2);    // dec_out_w^T bf16
    // aliases:
    float*  z_e  = t;
    float*  pval = (float*)xs;                          // NZF*16*4 (xs dead)
    int*    pidx = (int*)(xs + (size_t)NZF*16);

    hipMemsetAsync(cnt, 0, (size_t)NE*4, stream);
    hipMemsetAsync(sse, 0, 8, stream);

    dim3 gDE(DE/128, BB/128);    // (16,64)
    dim3 gIN(INW/128, BB/128);   // (8,64)
    dim3 gVQ(NE/128, NZF/128);   // (16,256)

    // ---- encoder: numpy-f32-exact semantics ----
    prep_xs<<<2048, 256, 0, stream>>>(x, scale, shift, xs);
    gemm_f32<0><<<gDE, 256, 0, stream>>>(xs, INW, nullptr, 0, enc_in_w, enc_in_b, h, DE);
    for (int r = 0; r < NRES; ++r) {
        gemm_f32<0><<<gDE, 256, 0, stream>>>(h, DE, nullptr, 0, enc_res_w, enc_res_b, t, DE);
        ln_np<0><<<BB, 64, 0, stream>>>(t, h, nullptr, enc_ln_g, enc_ln_b);
    }
    idx_embed_np<<<BB, 128, 0, stream>>>(bidx, lay, lty, wty, fcw, fcb, oww, owb, oidx);
    gemm_f32<1><<<gDE, 256, 0, stream>>>(h, DE, oidx, ODIM, catw, catb, z_e, DE);
    // ---- VQ: numpy-f32 dists + first-min argmin ----
    transCB<<<dim3(NE/32, ED/32), 256, 0, stream>>>(cbk, cbT);
    sqnorm_np<<<NZF/256, 256, 0, stream>>>(z_e, NZF, szv);
    sqnorm_np<<<NE/256, 256, 0, stream>>>(cbk, NE, scv);
    vq128<<<gVQ, 256, 0, stream>>>(z_e, cbT, szv, scv, pval, pidx);
    vq_reduce<<<NZF/256, 256, 0, stream>>>(pval, pidx, idxw, out + IDX_OFF, cnt);
    zq_loss<<<2048, 256, 0, stream>>>(idxw, cbk, z_e, out + ZQ_OFF, zqb, sse);
    finalize<<<1, 256, 0, stream>>>(cnt, sse, out);
    // ---- decoder: bf16 MFMA (loose thresholds) ----
    transW<<<dim3(DE/32, DE/32), 256, 0, stream>>>(dec_in_w,  wt1, DE, DE);
    transW<<<dim3(DE/32, DE/32), 256, 0, stream>>>(dec_res_w, wt2, DE, DE);
    transW<<<dim3(INW/32, DE/32), 256, 0, stream>>>(dec_out_w, wt3, DE, INW);
    gemm_bf16<2><<<gDE, 256, 0, stream>>>(zqb, wt1, dec_in_b, nullptr, nullptr, h, hb, DE, DE);
    for (int r = 0; r < NRES; ++r) {
        gemm_bf16<0><<<gDE, 256, 0, stream>>>(hb, wt2, dec_res_b, nullptr, nullptr, t, nullptr, DE, DE);
        ln_np<1><<<BB, 64, 0, stream>>>(t, h, hb, dec_ln_g, dec_ln_b);
    }
    gemm_bf16<1><<<gIN, 256, 0, stream>>>(hb, wt3, dec_out_b, scale, shift, out + XHAT_OFF, nullptr, INW, DE);
}

// Round 9
// 11074.252 us; speedup vs baseline: 7.5942x; 1.1453x over previous
//
#include <hip/hip_runtime.h>
#include <math.h>

#define BB 8192
#define INW 1024
#define DE 2048
#define NRES 4
#define NE 2048
#define ED 512
#define HID 128
#define ODIM 64
#define NZF (BB*4)
#define EPSLN 1e-5f

// d_out layout: loss, x_hat(B*IN), perplexity, z_q_st(B*DE), idx(NZF)
#define XHAT_OFF 1
#define PERP_OFF (1 + BB*INW)
#define ZQ_OFF   (PERP_OFF + 1)
#define IDX_OFF  (ZQ_OFF + BB*DE)

typedef short bf16x8 __attribute__((ext_vector_type(8)));
typedef float f32x4 __attribute__((ext_vector_type(4)));

__device__ __forceinline__ ushort f2b(float f) {
    unsigned u = __float_as_uint(f);
    unsigned r = (u + 0x7FFFu + ((u >> 16) & 1u)) >> 16;
    return (ushort)r;
}

// async global->LDS, 16B per lane; lds base must be wave-uniform (HW adds lane*16)
__device__ __forceinline__ void gl2lds16(const void* g, void* l) {
    __builtin_amdgcn_global_load_lds(
        (__attribute__((address_space(1))) void*)(g),
        (__attribute__((address_space(3))) void*)(l), 16, 0, 0);
}

// ---------------- prep: xs = (x - shift) / scale (np f32 semantics) ----------------
__global__ __launch_bounds__(256) void prep_xs(const float* __restrict__ x,
    const float* __restrict__ scale, const float* __restrict__ shift,
    float* __restrict__ xs)
{
    const long total = (long)BB*INW;
    for (long g = (long)blockIdx.x*256 + threadIdx.x; g < total; g += (long)gridDim.x*256) {
        int k = (int)(g & (INW-1));
        xs[g] = __fdiv_rn(__fsub_rn(x[g], shift[k]), scale[k]);
    }
}

// ================= fast f32 GEMM, np/BLAS-exact per-element FMA chain =================
// C[m][n] = (sum_k ascending, single fmaf chain) + bias[n].  128x128 tile, 8x8 micro.
// W staged via global_load_lds into unpadded [16][128]; A reg-staged transposed.
// amdgpu_num_vgpr(168): measured natural demand with DMA-W ~162 (cap 160 spilled ~2 regs,
// round 8: WRITE_SIZE 520MB scratch). 168 -> no spill, floor(512/168)=3 waves/SIMD.
template<int HASA2>
__global__ __launch_bounds__(256) __attribute__((amdgpu_num_vgpr(168)))
void gemm_f32(
    const float* __restrict__ A1, int K1, const float* __restrict__ A2, int K2,
    const float* __restrict__ W, const float* __restrict__ bias,
    float* __restrict__ C, int N)
{
    __shared__ float As[2][16][132];
    __shared__ float Ws[2][16][128];
    const int tid = threadIdx.x;
    const int tx = tid & 15, ty = tid >> 4;
    const int bm = blockIdx.y * 128, bn = blockIdx.x * 128;
    const int K = K1 + K2;
    const int ar = tid >> 1, aq = tid & 1;          // A staging: row, k-half
    const int wv = tid >> 6, lane = tid & 63;       // W staging via lds-DMA
    const int wrow = wv*4 + (lane >> 5);            // tile k-row (+2 for q=1)
    const int wcol = (lane & 31) * 4;               // tile col

    float acc[8][8];
#pragma unroll
    for (int i=0;i<8;i++)
#pragma unroll
      for (int j=0;j<8;j++) acc[i][j] = 0.0f;

    float4 ra0, ra1;
    // prologue: stage tile 0
    gl2lds16(W + (size_t)(wrow    )*N + bn + wcol, &Ws[0][0][0] + wv*512);
    gl2lds16(W + (size_t)(wrow + 2)*N + bn + wcol, &Ws[0][0][0] + wv*512 + 256);
    {
        const float4* p = (const float4*)(A1 + (size_t)(bm+ar)*K1 + aq*8);
        ra0 = p[0]; ra1 = p[1];
        As[0][aq*8+0][ar] = ra0.x; As[0][aq*8+1][ar] = ra0.y;
        As[0][aq*8+2][ar] = ra0.z; As[0][aq*8+3][ar] = ra0.w;
        As[0][aq*8+4][ar] = ra1.x; As[0][aq*8+5][ar] = ra1.y;
        As[0][aq*8+6][ar] = ra1.z; As[0][aq*8+7][ar] = ra1.w;
    }
    __syncthreads();

    int cur = 0;
    for (int k0 = 0; k0 < K; k0 += 16) {
        int kn = k0 + 16;
        int nb = cur ^ 1;
        if (kn < K) {
            // W -> LDS DMA (async, lands before next barrier)
            gl2lds16(W + (size_t)(kn + wrow    )*N + bn + wcol, &Ws[nb][0][0] + wv*512);
            gl2lds16(W + (size_t)(kn + wrow + 2)*N + bn + wcol, &Ws[nb][0][0] + wv*512 + 256);
            // A -> regs
            const float* s;
            if (HASA2 && kn >= K1) s = A2 + (size_t)(bm+ar)*K2 + (kn - K1) + aq*8;
            else                   s = A1 + (size_t)(bm+ar)*K1 + kn + aq*8;
            const float4* p = (const float4*)s;
            ra0 = p[0]; ra1 = p[1];
        }
#pragma unroll
        for (int kk = 0; kk < 16; ++kk) {
            float4 va0 = *(const float4*)&As[cur][kk][ty*4];
            float4 va1 = *(const float4*)&As[cur][kk][64 + ty*4];
            float4 vb0 = *(const float4*)&Ws[cur][kk][tx*4];
            float4 vb1 = *(const float4*)&Ws[cur][kk][64 + tx*4];
            float av[8] = {va0.x,va0.y,va0.z,va0.w, va1.x,va1.y,va1.z,va1.w};
            float bv[8] = {vb0.x,vb0.y,vb0.z,vb0.w, vb1.x,vb1.y,vb1.z,vb1.w};
#pragma unroll
            for (int i=0;i<8;i++)
#pragma unroll
                for (int j=0;j<8;j++)
                    acc[i][j] = fmaf(av[i], bv[j], acc[i][j]);
        }
        if (kn < K) {
            As[nb][aq*8+0][ar] = ra0.x; As[nb][aq*8+1][ar] = ra0.y;
            As[nb][aq*8+2][ar] = ra0.z; As[nb][aq*8+3][ar] = ra0.w;
            As[nb][aq*8+4][ar] = ra1.x; As[nb][aq*8+5][ar] = ra1.y;
            As[nb][aq*8+6][ar] = ra1.z; As[nb][aq*8+7][ar] = ra1.w;
        }
        __syncthreads();
        cur ^= 1;
    }
    // epilogue
    float4 bv0 = *(const float4*)&bias[bn + tx*4];
    float4 bv1 = *(const float4*)&bias[bn + 64 + tx*4];
    const float bb[8] = {bv0.x,bv0.y,bv0.z,bv0.w, bv1.x,bv1.y,bv1.z,bv1.w};
#pragma unroll
    for (int i=0;i<8;i++) {
        int gm = bm + ((i<4) ? ty*4+i : 64 + ty*4 + (i-4));
        float4 o0, o1;
        o0.x = __fadd_rn(acc[i][0], bb[0]); o0.y = __fadd_rn(acc[i][1], bb[1]);
        o0.z = __fadd_rn(acc[i][2], bb[2]); o0.w = __fadd_rn(acc[i][3], bb[3]);
        o1.x = __fadd_rn(acc[i][4], bb[4]); o1.y = __fadd_rn(acc[i][5], bb[5]);
        o1.z = __fadd_rn(acc[i][6], bb[6]); o1.w = __fadd_rn(acc[i][7], bb[7]);
        *(float4*)&C[(size_t)gm*N + bn + tx*4]      = o0;
        *(float4*)&C[(size_t)gm*N + bn + 64 + tx*4] = o1;
    }
}

// ---------------- codebook transpose (exact copy): cbT[e][c] = cb[c][e] ----------------
__global__ __launch_bounds__(256) void transCB(const float* __restrict__ cbk,
    float* __restrict__ cbT)
{
    __shared__ float tile[32][33];
    int c0 = blockIdx.x*32, e0 = blockIdx.y*32;
    int txx = threadIdx.x & 31, tyy = threadIdx.x >> 5;
#pragma unroll
    for (int i=0;i<4;i++)
        tile[tyy + i*8][txx] = cbk[(size_t)(c0 + tyy + i*8)*ED + e0 + txx];
    __syncthreads();
#pragma unroll
    for (int i=0;i<4;i++)
        cbT[(size_t)(e0 + tyy + i*8)*NE + c0 + txx] = tile[txx][tyy + i*8];
}

// ================= fused VQ: 128x128 dists + shuffle first-min partial argmin =================
__global__ __launch_bounds__(256) __attribute__((amdgpu_num_vgpr(168)))
void vq128(const float* __restrict__ zf,
    const float* __restrict__ cbT, const float* __restrict__ sz, const float* __restrict__ sc,
    float* __restrict__ pval, int* __restrict__ pidx)
{
    __shared__ float Zs[2][16][132];
    __shared__ float Cs[2][16][128];
    const int tid = threadIdx.x;
    const int tx = tid & 15, ty = tid >> 4;
    const int br = blockIdx.y * 128, bc = blockIdx.x * 128;
    const int ar = tid >> 1, aq = tid & 1;
    const int wv = tid >> 6, lane = tid & 63;
    const int wrow = wv*4 + (lane >> 5);
    const int wcol = (lane & 31) * 4;

    float acc[8][8];
#pragma unroll
    for (int i=0;i<8;i++)
#pragma unroll
      for (int j=0;j<8;j++) acc[i][j] = 0.0f;

    float4 ra0, ra1;
    gl2lds16(cbT + (size_t)(wrow    )*NE + bc + wcol, &Cs[0][0][0] + wv*512);
    gl2lds16(cbT + (size_t)(wrow + 2)*NE + bc + wcol, &Cs[0][0][0] + wv*512 + 256);
    {
        const float4* p = (const float4*)(zf + (size_t)(br+ar)*ED + aq*8);
        ra0 = p[0]; ra1 = p[1];
        Zs[0][aq*8+0][ar] = ra0.x; Zs[0][aq*8+1][ar] = ra0.y;
        Zs[0][aq*8+2][ar] = ra0.z; Zs[0][aq*8+3][ar] = ra0.w;
        Zs[0][aq*8+4][ar] = ra1.x; Zs[0][aq*8+5][ar] = ra1.y;
        Zs[0][aq*8+6][ar] = ra1.z; Zs[0][aq*8+7][ar] = ra1.w;
    }
    __syncthreads();

    int cur = 0;
    for (int k0 = 0; k0 < ED; k0 += 16) {
        int kn = k0 + 16;
        int nb = cur ^ 1;
        if (kn < ED) {
            gl2lds16(cbT + (size_t)(kn + wrow    )*NE + bc + wcol, &Cs[nb][0][0] + wv*512);
            gl2lds16(cbT + (size_t)(kn + wrow + 2)*NE + bc + wcol, &Cs[nb][0][0] + wv*512 + 256);
            const float4* p = (const float4*)(zf + (size_t)(br+ar)*ED + kn + aq*8);
            ra0 = p[0]; ra1 = p[1];
        }
#pragma unroll
        for (int kk = 0; kk < 16; ++kk) {
            float4 va0 = *(const float4*)&Zs[cur][kk][ty*4];
            float4 va1 = *(const float4*)&Zs[cur][kk][64 + ty*4];
            float4 vb0 = *(const float4*)&Cs[cur][kk][tx*4];
            float4 vb1 = *(const float4*)&Cs[cur][kk][64 + tx*4];
            float av[8] = {va0.x,va0.y,va0.z,va0.w, va1.x,va1.y,va1.z,va1.w};
            float bv[8] = {vb0.x,vb0.y,vb0.z,vb0.w, vb1.x,vb1.y,vb1.z,vb1.w};
#pragma unroll
            for (int i=0;i<8;i++)
#pragma unroll
                for (int j=0;j<8;j++)
                    acc[i][j] = fmaf(av[i], bv[j], acc[i][j]);
        }
        if (kn < ED) {
            Zs[nb][aq*8+0][ar] = ra0.x; Zs[nb][aq*8+1][ar] = ra0.y;
            Zs[nb][aq*8+2][ar] = ra0.z; Zs[nb][aq*8+3][ar] = ra0.w;
            Zs[nb][aq*8+4][ar] = ra1.x; Zs[nb][aq*8+5][ar] = ra1.y;
            Zs[nb][aq*8+6][ar] = ra1.z; Zs[nb][aq*8+7][ar] = ra1.w;
        }
        __syncthreads();
        cur ^= 1;
    }
    // dists + first-min: per-thread over its 8 cols, then 16-lane shuffle tree.
    // lexicographic (val, idx) min == np.argmin first-min semantics.
#pragma unroll
    for (int i=0;i<8;i++) {
        int lr = (i<4) ? ty*4+i : 64 + ty*4 + (i-4);
        float szi = sz[br + lr];
        float bvv = 0.0f; int bii = -1;
#pragma unroll
        for (int j=0;j<8;j++) {
            int lc = (j<4) ? tx*4+j : 64 + tx*4 + (j-4);
            int gc = bc + lc;
            float d = __fsub_rn(__fadd_rn(szi, sc[gc]), __fmul_rn(2.0f, acc[i][j]));
            if (bii < 0 || d < bvv || (d == bvv && gc < bii)) { bvv = d; bii = gc; }
        }
#pragma unroll
        for (int off = 8; off; off >>= 1) {
            float ov = __shfl_xor(bvv, off);
            int   oi = __shfl_xor(bii, off);
            if (ov < bvv || (ov == bvv && oi < bii)) { bvv = ov; bii = oi; }
        }
        if (tx == 0) {
            pval[(size_t)(br+lr)*16 + blockIdx.x] = bvv;
            pidx[(size_t)(br+lr)*16 + blockIdx.x] = bii;
        }
    }
}

// ================= bf16 MFMA GEMM (decoder only; loose thresholds) =================
template<int EPI>
__global__ __launch_bounds__(256) void gemm_bf16(
    const ushort* __restrict__ X, const ushort* __restrict__ WT,
    const float* __restrict__ bias, const float* __restrict__ esc,
    const float* __restrict__ esh, float* __restrict__ C,
    ushort* __restrict__ Cb, int N, int K)
{
    __shared__ ushort Xs[2][128][40];
    __shared__ ushort Ws[2][128][40];
    const int tid = threadIdx.x;
    const int lane = tid & 63, wave = tid >> 6;
    const int wr = wave >> 1, wc = wave & 1;
    const int bm = blockIdx.y * 128, bn = blockIdx.x * 128;
    const int sr = tid >> 1, sh = tid & 1;

    f32x4 acc[4][4];
#pragma unroll
    for (int m=0;m<4;m++)
#pragma unroll
      for (int n=0;n<4;n++) acc[m][n] = (f32x4){0.f,0.f,0.f,0.f};

    float4 xv0, xv1, wv0, wv1;
    {
        const float4* xp = (const float4*)(X + (size_t)(bm+sr)*K + sh*16);
        xv0 = xp[0]; xv1 = xp[1];
        const float4* wp = (const float4*)(WT + (size_t)(bn+sr)*K + sh*16);
        wv0 = wp[0]; wv1 = wp[1];
    }
    {
        float4* dx = (float4*)&Xs[0][sr][sh*16]; dx[0] = xv0; dx[1] = xv1;
        float4* dw = (float4*)&Ws[0][sr][sh*16]; dw[0] = wv0; dw[1] = wv1;
    }
    __syncthreads();

    const int ko = (lane >> 4) * 8;
    const int fr = lane & 15;
    int cur = 0;
    for (int k0 = 0; k0 < K; k0 += 32) {
        int kn = k0 + 32;
        if (kn < K) {
            const float4* xp = (const float4*)(X + (size_t)(bm+sr)*K + kn + sh*16);
            xv0 = xp[0]; xv1 = xp[1];
            const float4* wp = (const float4*)(WT + (size_t)(bn+sr)*K + kn + sh*16);
            wv0 = wp[0]; wv1 = wp[1];
        }
        bf16x8 af[4], bfr[4];
#pragma unroll
        for (int m=0;m<4;m++) af[m]  = *(const bf16x8*)&Xs[cur][wr*64 + m*16 + fr][ko];
#pragma unroll
        for (int n=0;n<4;n++) bfr[n] = *(const bf16x8*)&Ws[cur][wc*64 + n*16 + fr][ko];
#pragma unroll
        for (int m=0;m<4;m++)
#pragma unroll
            for (int n=0;n<4;n++)
                acc[m][n] = __builtin_amdgcn_mfma_f32_16x16x32_bf16(af[m], bfr[n], acc[m][n], 0, 0, 0);
        if (kn < K) {
            int nb = cur ^ 1;
            float4* dx = (float4*)&Xs[nb][sr][sh*16]; dx[0] = xv0; dx[1] = xv1;
            float4* dw = (float4*)&Ws[nb][sr][sh*16]; dw[0] = wv0; dw[1] = wv1;
        }
        __syncthreads();
        cur ^= 1;
    }
    const int cr = (lane >> 4) * 4, cc = lane & 15;
#pragma unroll
    for (int m=0;m<4;m++) {
#pragma unroll
        for (int n=0;n<4;n++) {
            int gn = bn + wc*64 + n*16 + cc;
            float bb = bias[gn];
            float s0 = 0.f, s1 = 0.f;
            if (EPI == 1) { s0 = esc[gn]; s1 = esh[gn]; }
#pragma unroll
            for (int r=0;r<4;r++) {
                int gm = bm + wr*64 + m*16 + cr + r;
                float v = acc[m][n][r] + bb;
                if (EPI == 1) v = s0*v + s1;
                size_t off = (size_t)gm*N + gn;
                C[off] = v;
                if (EPI == 2) Cb[off] = f2b(v);
            }
        }
    }
}

// ---------------- weight transpose + f32->bf16: WT[n][k] = bf16(W[k][n]) ----------------
__global__ __launch_bounds__(256) void transW(const float* __restrict__ W,
    ushort* __restrict__ WT, int K, int N)
{
    __shared__ float tile[32][33];
    int n0 = blockIdx.x*32, k0 = blockIdx.y*32;
    int tx = threadIdx.x & 31, ty8 = threadIdx.x >> 5;
#pragma unroll
    for (int i=0;i<4;i++)
        tile[ty8 + i*8][tx] = W[(size_t)(k0 + ty8 + i*8)*N + n0 + tx];
    __syncthreads();
#pragma unroll
    for (int i=0;i<4;i++) {
        int n = ty8 + i*8;
        WT[(size_t)(n0+n)*K + k0 + tx] = f2b(tile[tx][n]);
    }
}

// ---------------- LayerNorm + relu + add, numpy-f32-exact; WB=1 also writes bf16 mirror ----------------
template<int WB>
__global__ __launch_bounds__(64) void ln_np(const float* __restrict__ t,
    float* __restrict__ h, ushort* __restrict__ hb,
    const float* __restrict__ g, const float* __restrict__ be)
{
    const int row = blockIdx.x;
    const float* tr = t + (long)row*DE;
    float* hr = h + (long)row*DE;
    __shared__ float bs[16];
    __shared__ float mv[2];
    const int l = threadIdx.x;

    if (l < 16) {
        const float* p = tr + l*128;
        float r[8];
#pragma unroll
        for (int j=0;j<8;j++) r[j] = p[j];
        for (int i=8;i<128;i+=8)
#pragma unroll
            for (int j=0;j<8;j++) r[j] = __fadd_rn(r[j], p[i+j]);
        float tA = __fadd_rn(__fadd_rn(r[0],r[1]), __fadd_rn(r[2],r[3]));
        float tB = __fadd_rn(__fadd_rn(r[4],r[5]), __fadd_rn(r[6],r[7]));
        bs[l] = __fadd_rn(tA, tB);
    }
    __syncthreads();
    if (l == 0) {
        float s8[8], s4[4], s2[2];
#pragma unroll
        for (int i=0;i<8;i++) s8[i] = __fadd_rn(bs[2*i], bs[2*i+1]);
#pragma unroll
        for (int i=0;i<4;i++) s4[i] = __fadd_rn(s8[2*i], s8[2*i+1]);
#pragma unroll
        for (int i=0;i<2;i++) s2[i] = __fadd_rn(s4[2*i], s4[2*i+1]);
        mv[0] = __fdiv_rn(__fadd_rn(s2[0], s2[1]), 2048.0f);
    }
    __syncthreads();
    const float m = mv[0];
    if (l < 16) {
        const float* p = tr + l*128;
        float r[8];
#pragma unroll
        for (int j=0;j<8;j++) { float d = __fsub_rn(p[j], m); r[j] = __fmul_rn(d, d); }
        for (int i=8;i<128;i+=8)
#pragma unroll
            for (int j=0;j<8;j++) {
                float d = __fsub_rn(p[i+j], m);
                r[j] = __fadd_rn(r[j], __fmul_rn(d, d));
            }
        float tA = __fadd_rn(__fadd_rn(r[0],r[1]), __fadd_rn(r[2],r[3]));
        float tB = __fadd_rn(__fadd_rn(r[4],r[5]), __fadd_rn(r[6],r[7]));
        bs[l] = __fadd_rn(tA, tB);
    }
    __syncthreads();
    if (l == 0) {
        float s8[8], s4[4], s2[2];
#pragma unroll
        for (int i=0;i<8;i++) s8[i] = __fadd_rn(bs[2*i], bs[2*i+1]);
#pragma unroll
        for (int i=0;i<4;i++) s4[i] = __fadd_rn(s8[2*i], s8[2*i+1]);
#pragma unroll
        for (int i=0;i<2;i++) s2[i] = __fadd_rn(s4[2*i], s4[2*i+1]);
        float v = __fdiv_rn(__fadd_rn(s2[0], s2[1]), 2048.0f);
        mv[1] = __fdiv_rn(1.0f, __fsqrt_rn(__fadd_rn(v, EPSLN)));
    }
    __syncthreads();
    const float rs = mv[1];
    ushort* hbr = (WB ? hb + (long)row*DE : nullptr);
    for (int j = l; j < DE; j += 64) {
        float u = __fadd_rn(__fmul_rn(__fmul_rn(__fsub_rn(tr[j], m), rs), g[j]), be[j]);
        float r = u > 0.0f ? u : 0.0f;
        float nh = __fadd_rn(hr[j], r);
        hr[j] = nh;
        if (WB) hbr[j] = f2b(nh);
    }
}

// ---------------- IdxEmbedding, np-f32 ----------------
__global__ __launch_bounds__(128) void idx_embed_np(const int* __restrict__ bidx,
    const float* __restrict__ lay, const float* __restrict__ lty, const float* __restrict__ wty,
    const float* __restrict__ fw, const float* __restrict__ fb,
    const float* __restrict__ ow, const float* __restrict__ ob,
    float* __restrict__ oidx)
{
    const int row = blockIdx.x;
    __shared__ float emb[3*HID+3];
    __shared__ float fcv[HID];
    const int t = threadIdx.x;
    int c0 = bidx[row*6+0], c1 = bidx[row*6+1], c2 = bidx[row*6+2];
    emb[t]       = lay[c0*HID + t];
    emb[HID+t]   = lty[c1*HID + t];
    emb[2*HID+t] = wty[c2*HID + t];
    if (t < 3) emb[3*HID+t] = (float)bidx[row*6+3+t];
    __syncthreads();
    {
        float acc = 0.0f;
        for (int k = 0; k < 3*HID+3; ++k)
            acc = fmaf(emb[k], fw[k*HID + t], acc);
        fcv[t] = __fadd_rn(acc, fb[t]);
    }
    __syncthreads();
    if (t < ODIM) {
        float acc = 0.0f;
        for (int k = 0; k < HID; ++k)
            acc = fmaf(fcv[k], ow[k*ODIM + t], acc);
        oidx[(long)row*ODIM + t] = __fadd_rn(acc, ob[t]);
    }
}

// ---------------- squared row norms, numpy pairwise (4 blocks of 128) ----------------
__global__ __launch_bounds__(256) void sqnorm_np(const float* __restrict__ a, int nrows,
    float* __restrict__ outv)
{
    int rI = blockIdx.x*256 + threadIdx.x;
    if (rI >= nrows) return;
    const float* p = a + (long)rI*ED;
    float B[4];
#pragma unroll
    for (int b = 0; b < 4; ++b) {
        const float* q = p + b*128;
        float r[8];
#pragma unroll
        for (int j=0;j<8;j++) r[j] = __fmul_rn(q[j], q[j]);
        for (int i=8;i<128;i+=8)
#pragma unroll
            for (int j=0;j<8;j++) r[j] = __fadd_rn(r[j], __fmul_rn(q[i+j], q[i+j]));
        float tA = __fadd_rn(__fadd_rn(r[0],r[1]), __fadd_rn(r[2],r[3]));
        float tB = __fadd_rn(__fadd_rn(r[4],r[5]), __fadd_rn(r[6],r[7]));
        B[b] = __fadd_rn(tA, tB);
    }
    outv[rI] = __fadd_rn(__fadd_rn(B[0], B[1]), __fadd_rn(B[2], B[3]));
}

// ---------------- final argmin across 16 column blocks ----------------
__global__ __launch_bounds__(256) void vq_reduce(const float* __restrict__ pval,
    const int* __restrict__ pidx, int* __restrict__ idxw, float* __restrict__ idxf,
    int* __restrict__ cnt)
{
    int r = blockIdx.x*256 + threadIdx.x;
    const float* pv = pval + (long)r*16;
    const int*   pi = pidx + (long)r*16;
    float best = pv[0]; int bj = pi[0];
#pragma unroll
    for (int c = 1; c < 16; ++c) {
        float v = pv[c]; int ii = pi[c];
        if (v < best || (v == best && ii < bj)) { best = v; bj = ii; }
    }
    idxw[r] = bj;
    idxf[r] = (float)bj;
    atomicAdd(&cnt[bj], 1);
}

// ---------------- z_q_st + bf16 mirror + SSE accumulation ----------------
__global__ __launch_bounds__(256) void zq_loss(const int* __restrict__ idxw,
    const float* __restrict__ cbk, const float* __restrict__ z_e,
    float* __restrict__ zq_out, ushort* __restrict__ zqb, double* __restrict__ sse)
{
    double local = 0.0;
    const long total = (long)NZF*ED;
    for (long g = (long)blockIdx.x*256 + threadIdx.x; g < total; g += (long)gridDim.x*256) {
        int p = (int)(g >> 9);
        int e = (int)(g & 511);
        float q = cbk[(long)idxw[p]*ED + e];
        float z = z_e[g];
        float d = __fsub_rn(q, z);
        float o = __fadd_rn(z, d);
        zq_out[g] = o;
        zqb[g] = f2b(o);
        local += (double)d * (double)d;
    }
    for (int off = 32; off > 0; off >>= 1) local += __shfl_down(local, off);
    __shared__ double red[4];
    int wid = threadIdx.x >> 6, lane = threadIdx.x & 63;
    if (lane == 0) red[wid] = local;
    __syncthreads();
    if (threadIdx.x == 0) atomicAdd(sse, red[0]+red[1]+red[2]+red[3]);
}

// ---------------- loss + perplexity ----------------
__global__ __launch_bounds__(256) void finalize(const int* __restrict__ cnt,
    const double* __restrict__ sse, float* __restrict__ d_out)
{
    double s = 0.0;
    for (int j = threadIdx.x; j < NE; j += 256) {
        double e = (double)cnt[j] / (double)NZF;
        s += e * log(e + 1e-10);
    }
    for (int off = 32; off > 0; off >>= 1) s += __shfl_down(s, off);
    __shared__ double red[4];
    int wid = threadIdx.x >> 6, lane = threadIdx.x & 63;
    if (lane == 0) red[wid] = s;
    __syncthreads();
    if (threadIdx.x == 0) {
        double st = red[0]+red[1]+red[2]+red[3];
        d_out[0]        = (float)(1.25 * sse[0] / (double)((long)BB*DE));
        d_out[PERP_OFF] = (float)exp(-st);
    }
}

extern "C" void kernel_launch(void* const* d_in, const int* in_sizes, int n_in,
                              void* d_out_v, int out_size, void* d_ws, size_t ws_size,
                              hipStream_t stream)
{
    const float* x         = (const float*)d_in[0];
    const int*   bidx      = (const int*)  d_in[1];
    const float* scale     = (const float*)d_in[2];
    const float* shift     = (const float*)d_in[3];
    const float* enc_in_w  = (const float*)d_in[4];
    const float* enc_in_b  = (const float*)d_in[5];
    const float* enc_res_w = (const float*)d_in[6];
    const float* enc_res_b = (const float*)d_in[7];
    const float* enc_ln_g  = (const float*)d_in[8];
    const float* enc_ln_b  = (const float*)d_in[9];
    const float* lay       = (const float*)d_in[10];
    const float* lty       = (const float*)d_in[11];
    const float* wty       = (const float*)d_in[12];
    const float* fcw       = (const float*)d_in[13];
    const float* fcb       = (const float*)d_in[14];
    const float* oww       = (const float*)d_in[15];
    const float* owb       = (const float*)d_in[16];
    const float* catw      = (const float*)d_in[17];
    const float* catb      = (const float*)d_in[18];
    const float* cbk       = (const float*)d_in[19];
    const float* dec_in_w  = (const float*)d_in[20];
    const float* dec_in_b  = (const float*)d_in[21];
    const float* dec_res_w = (const float*)d_in[22];
    const float* dec_res_b = (const float*)d_in[23];
    const float* dec_ln_g  = (const float*)d_in[24];
    const float* dec_ln_b  = (const float*)d_in[25];
    const float* dec_out_w = (const float*)d_in[26];
    const float* dec_out_b = (const float*)d_in[27];
    float* out = (float*)d_out_v;

    char* w = (char*)d_ws;
    auto alloc = [&](size_t bytes) {
        char* p = w;
        w += (bytes + 255) & ~(size_t)255;
        return p;
    };
    float*  xs   = (float*)alloc((size_t)BB*INW*4);     // dead after enc_in GEMM
    float*  h    = (float*)alloc((size_t)BB*DE*4);
    float*  t    = (float*)alloc((size_t)BB*DE*4);
    float*  oidx = (float*)alloc((size_t)BB*ODIM*4);
    int*    idxw = (int*)  alloc((size_t)NZF*4);
    float*  szv  = (float*)alloc((size_t)NZF*4);
    float*  scv  = (float*)alloc((size_t)NE*4);
    int*    cnt  = (int*)  alloc((size_t)NE*4);
    double* sse  = (double*)alloc(8);
    float*  cbT  = (float*)alloc((size_t)ED*NE*4);      // 4MB transposed codebook
    ushort* zqb  = (ushort*)alloc((size_t)BB*DE*2);     // bf16 z_q_st
    ushort* hb   = (ushort*)alloc((size_t)BB*DE*2);     // bf16 decoder hidden
    ushort* wt1  = (ushort*)alloc((size_t)DE*DE*2);     // dec_in_w^T bf16
    ushort* wt2  = (ushort*)alloc((size_t)DE*DE*2);     // dec_res_w^T bf16
    ushort* wt3  = (ushort*)alloc((size_t)INW*DE*2);    // dec_out_w^T bf16
    // aliases:
    float*  z_e  = t;
    float*  pval = (float*)xs;                          // NZF*16*4 (xs dead)
    int*    pidx = (int*)(xs + (size_t)NZF*16);

    hipMemsetAsync(cnt, 0, (size_t)NE*4, stream);
    hipMemsetAsync(sse, 0, 8, stream);

    dim3 gDE(DE/128, BB/128);    // (16,64)
    dim3 gIN(INW/128, BB/128);   // (8,64)
    dim3 gVQ(NE/128, NZF/128);   // (16,256)

    // ---- encoder: numpy-f32-exact semantics ----
    prep_xs<<<2048, 256, 0, stream>>>(x, scale, shift, xs);
    gemm_f32<0><<<gDE, 256, 0, stream>>>(xs, INW, nullptr, 0, enc_in_w, enc_in_b, h, DE);
    for (int r = 0; r < NRES; ++r) {
        gemm_f32<0><<<gDE, 256, 0, stream>>>(h, DE, nullptr, 0, enc_res_w, enc_res_b, t, DE);
        ln_np<0><<<BB, 64, 0, stream>>>(t, h, nullptr, enc_ln_g, enc_ln_b);
    }
    idx_embed_np<<<BB, 128, 0, stream>>>(bidx, lay, lty, wty, fcw, fcb, oww, owb, oidx);
    gemm_f32<1><<<gDE, 256, 0, stream>>>(h, DE, oidx, ODIM, catw, catb, z_e, DE);
    // ---- VQ: numpy-f32 dists + first-min argmin ----
    transCB<<<dim3(NE/32, ED/32), 256, 0, stream>>>(cbk, cbT);
    sqnorm_np<<<NZF/256, 256, 0, stream>>>(z_e, NZF, szv);
    sqnorm_np<<<NE/256, 256, 0, stream>>>(cbk, NE, scv);
    vq128<<<gVQ, 256, 0, stream>>>(z_e, cbT, szv, scv, pval, pidx);
    vq_reduce<<<NZF/256, 256, 0, stream>>>(pval, pidx, idxw, out + IDX_OFF, cnt);
    zq_loss<<<2048, 256, 0, stream>>>(idxw, cbk, z_e, out + ZQ_OFF, zqb, sse);
    finalize<<<1, 256, 0, stream>>>(cnt, sse, out);
    // ---- decoder: bf16 MFMA (loose thresholds) ----
    transW<<<dim3(DE/32, DE/32), 256, 0, stream>>>(dec_in_w,  wt1, DE, DE);
    transW<<<dim3(DE/32, DE/32), 256, 0, stream>>>(dec_res_w, wt2, DE, DE);
    transW<<<dim3(INW/32, DE/32), 256, 0, stream>>>(dec_out_w, wt3, DE, INW);
    gemm_bf16<2><<<gDE, 256, 0, stream>>>(zqb, wt1, dec_in_b, nullptr, nullptr, h, hb, DE, DE);
    for (int r = 0; r < NRES; ++r) {
        gemm_bf16<0><<<gDE, 256, 0, stream>>>(hb, wt2, dec_res_b, nullptr, nullptr, t, nullptr, DE, DE);
        ln_np<1><<<BB, 64, 0, stream>>>(t, h, hb, dec_ln_g, dec_ln_b);
    }
    gemm_bf16<1><<<gIN, 256, 0, stream>>>(hb, wt3, dec_out_b, scale, shift, out + XHAT_OFF, nullptr, INW, DE);
}

// Round 10
// 6818.949 us; speedup vs baseline: 12.3333x; 1.6240x over previous
//
#include <hip/hip_runtime.h>
#include <math.h>

#define BB 8192
#define INW 1024
#define DE 2048
#define NRES 4
#define NE 2048
#define ED 512
#define HID 128
#define ODIM 64
#define NZF (BB*4)
#define EPSLN 1e-5f

// d_out layout: loss, x_hat(B*IN), perplexity, z_q_st(B*DE), idx(NZF)
#define XHAT_OFF 1
#define PERP_OFF (1 + BB*INW)
#define ZQ_OFF   (PERP_OFF + 1)
#define IDX_OFF  (ZQ_OFF + BB*DE)

typedef short bf16x8 __attribute__((ext_vector_type(8)));
typedef float f32x4 __attribute__((ext_vector_type(4)));

__device__ __forceinline__ ushort f2b(float f) {
    unsigned u = __float_as_uint(f);
    unsigned r = (u + 0x7FFFu + ((u >> 16) & 1u)) >> 16;
    return (ushort)r;
}

// ---------------- prep: xs = (x - shift) / scale (np f32 semantics) ----------------
__global__ __launch_bounds__(256) void prep_xs(const float* __restrict__ x,
    const float* __restrict__ scale, const float* __restrict__ shift,
    float* __restrict__ xs)
{
    const long total = (long)BB*INW;
    for (long g = (long)blockIdx.x*256 + threadIdx.x; g < total; g += (long)gridDim.x*256) {
        int k = (int)(g & (INW-1));
        xs[g] = __fdiv_rn(__fsub_rn(x[g], shift[k]), scale[k]);
    }
}

// ================= fast f32 GEMM, np/BLAS-exact per-element FMA chain =================
// 512 threads, 128x128 tile, 8x4 microtile -> 32-reg accumulator. Per-element chain
// unchanged (single thread, ascending k). amdgpu_num_vgpr(128): 4 waves/SIMD boundary
// (gfx950 occupancy steps at 64/128/256 only -- round 9 proved 168 VGPR still = 2 waves).
template<int HASA2>
__global__ __launch_bounds__(512) __attribute__((amdgpu_num_vgpr(128)))
void gemm_f32(
    const float* __restrict__ A1, int K1, const float* __restrict__ A2, int K2,
    const float* __restrict__ W, const float* __restrict__ bias,
    float* __restrict__ C, int N)
{
    __shared__ float As[2][16][132];   // transposed A tile [k][m], +4 pad
    __shared__ float Ws[2][16][128];   // W tile [k][n]
    const int tid = threadIdx.x;
    const int tx = tid & 31, ty = tid >> 5;        // micro: 4 cols, 8 rows
    const int bm = blockIdx.y * 128, bn = blockIdx.x * 128;
    const int K = K1 + K2;
    const int ar = tid >> 2, aq = tid & 3;         // A stage: row 0..127, k-quarter
    const int wk = tid >> 5, wc4 = (tid & 31) * 4; // W stage: k-row, col4

    float acc[8][4];
#pragma unroll
    for (int i=0;i<8;i++)
#pragma unroll
      for (int j=0;j<4;j++) acc[i][j] = 0.0f;

    float4 ra, rw;
    // prologue: stage tile 0
    ra = *(const float4*)(A1 + (size_t)(bm+ar)*K1 + aq*4);
    rw = *(const float4*)(W + (size_t)wk*N + bn + wc4);
    As[0][aq*4+0][ar] = ra.x; As[0][aq*4+1][ar] = ra.y;
    As[0][aq*4+2][ar] = ra.z; As[0][aq*4+3][ar] = ra.w;
    *(float4*)&Ws[0][wk][wc4] = rw;
    __syncthreads();

    int cur = 0;
    for (int k0 = 0; k0 < K; k0 += 16) {
        int kn = k0 + 16;
        int nb = cur ^ 1;
        if (kn < K) {
            const float* s;
            if (HASA2 && kn >= K1) s = A2 + (size_t)(bm+ar)*K2 + (kn - K1) + aq*4;
            else                   s = A1 + (size_t)(bm+ar)*K1 + kn + aq*4;
            ra = *(const float4*)s;
            rw = *(const float4*)(W + (size_t)(kn+wk)*N + bn + wc4);
        }
#pragma unroll
        for (int kk = 0; kk < 16; ++kk) {
            float4 va0 = *(const float4*)&As[cur][kk][ty*8];
            float4 va1 = *(const float4*)&As[cur][kk][ty*8 + 4];
            float4 vb  = *(const float4*)&Ws[cur][kk][tx*4];
            float av[8] = {va0.x,va0.y,va0.z,va0.w, va1.x,va1.y,va1.z,va1.w};
            float bv[4] = {vb.x,vb.y,vb.z,vb.w};
#pragma unroll
            for (int i=0;i<8;i++)
#pragma unroll
                for (int j=0;j<4;j++)
                    acc[i][j] = fmaf(av[i], bv[j], acc[i][j]);
        }
        if (kn < K) {
            As[nb][aq*4+0][ar] = ra.x; As[nb][aq*4+1][ar] = ra.y;
            As[nb][aq*4+2][ar] = ra.z; As[nb][aq*4+3][ar] = ra.w;
            *(float4*)&Ws[nb][wk][wc4] = rw;
        }
        __syncthreads();
        cur ^= 1;
    }
    // epilogue
    float4 bv = *(const float4*)&bias[bn + tx*4];
    const float bb[4] = {bv.x, bv.y, bv.z, bv.w};
#pragma unroll
    for (int i=0;i<8;i++) {
        int gm = bm + ty*8 + i;
        float4 o;
        o.x = __fadd_rn(acc[i][0], bb[0]);
        o.y = __fadd_rn(acc[i][1], bb[1]);
        o.z = __fadd_rn(acc[i][2], bb[2]);
        o.w = __fadd_rn(acc[i][3], bb[3]);
        *(float4*)&C[(size_t)gm*N + bn + tx*4] = o;
    }
}

// ---------------- codebook transpose (exact copy): cbT[e][c] = cb[c][e] ----------------
__global__ __launch_bounds__(256) void transCB(const float* __restrict__ cbk,
    float* __restrict__ cbT)
{
    __shared__ float tile[32][33];
    int c0 = blockIdx.x*32, e0 = blockIdx.y*32;
    int txx = threadIdx.x & 31, tyy = threadIdx.x >> 5;
#pragma unroll
    for (int i=0;i<4;i++)
        tile[tyy + i*8][txx] = cbk[(size_t)(c0 + tyy + i*8)*ED + e0 + txx];
    __syncthreads();
#pragma unroll
    for (int i=0;i<4;i++)
        cbT[(size_t)(e0 + tyy + i*8)*NE + c0 + txx] = tile[txx][tyy + i*8];
}

// ================= fused VQ: 128x128 dists + shuffle first-min partial argmin =================
__global__ __launch_bounds__(512) __attribute__((amdgpu_num_vgpr(128)))
void vq128(const float* __restrict__ zf,
    const float* __restrict__ cbT, const float* __restrict__ sz, const float* __restrict__ sc,
    float* __restrict__ pval, int* __restrict__ pidx)
{
    __shared__ float Zs[2][16][132];
    __shared__ float Cs[2][16][128];
    const int tid = threadIdx.x;
    const int tx = tid & 31, ty = tid >> 5;
    const int br = blockIdx.y * 128, bc = blockIdx.x * 128;
    const int ar = tid >> 2, aq = tid & 3;
    const int wk = tid >> 5, wc4 = (tid & 31) * 4;

    float acc[8][4];
#pragma unroll
    for (int i=0;i<8;i++)
#pragma unroll
      for (int j=0;j<4;j++) acc[i][j] = 0.0f;

    float4 ra, rw;
    ra = *(const float4*)(zf + (size_t)(br+ar)*ED + aq*4);
    rw = *(const float4*)(cbT + (size_t)wk*NE + bc + wc4);
    Zs[0][aq*4+0][ar] = ra.x; Zs[0][aq*4+1][ar] = ra.y;
    Zs[0][aq*4+2][ar] = ra.z; Zs[0][aq*4+3][ar] = ra.w;
    *(float4*)&Cs[0][wk][wc4] = rw;
    __syncthreads();

    int cur = 0;
    for (int k0 = 0; k0 < ED; k0 += 16) {
        int kn = k0 + 16;
        int nb = cur ^ 1;
        if (kn < ED) {
            ra = *(const float4*)(zf + (size_t)(br+ar)*ED + kn + aq*4);
            rw = *(const float4*)(cbT + (size_t)(kn+wk)*NE + bc + wc4);
        }
#pragma unroll
        for (int kk = 0; kk < 16; ++kk) {
            float4 va0 = *(const float4*)&Zs[cur][kk][ty*8];
            float4 va1 = *(const float4*)&Zs[cur][kk][ty*8 + 4];
            float4 vb  = *(const float4*)&Cs[cur][kk][tx*4];
            float av[8] = {va0.x,va0.y,va0.z,va0.w, va1.x,va1.y,va1.z,va1.w};
            float bv[4] = {vb.x,vb.y,vb.z,vb.w};
#pragma unroll
            for (int i=0;i<8;i++)
#pragma unroll
                for (int j=0;j<4;j++)
                    acc[i][j] = fmaf(av[i], bv[j], acc[i][j]);
        }
        if (kn < ED) {
            Zs[nb][aq*4+0][ar] = ra.x; Zs[nb][aq*4+1][ar] = ra.y;
            Zs[nb][aq*4+2][ar] = ra.z; Zs[nb][aq*4+3][ar] = ra.w;
            *(float4*)&Cs[nb][wk][wc4] = rw;
        }
        __syncthreads();
        cur ^= 1;
    }
    // dists + first-min: per-thread over its 4 cols (ascending), then 32-lane
    // shuffle tree (offs 16..1 stay within ty-uniform wave halves).
    // lexicographic (val, idx) min == np.argmin first-min semantics.
#pragma unroll
    for (int i=0;i<8;i++) {
        int lr = ty*8 + i;
        float szi = sz[br + lr];
        float bvv = 0.0f; int bii = -1;
#pragma unroll
        for (int j=0;j<4;j++) {
            int gc = bc + tx*4 + j;
            float d = __fsub_rn(__fadd_rn(szi, sc[gc]), __fmul_rn(2.0f, acc[i][j]));
            if (bii < 0 || d < bvv || (d == bvv && gc < bii)) { bvv = d; bii = gc; }
        }
#pragma unroll
        for (int off = 16; off; off >>= 1) {
            float ov = __shfl_xor(bvv, off);
            int   oi = __shfl_xor(bii, off);
            if (ov < bvv || (ov == bvv && oi < bii)) { bvv = ov; bii = oi; }
        }
        if (tx == 0) {
            pval[(size_t)(br+lr)*16 + blockIdx.x] = bvv;
            pidx[(size_t)(br+lr)*16 + blockIdx.x] = bii;
        }
    }
}

// ================= bf16 MFMA GEMM (decoder only; loose thresholds) =================
template<int EPI>
__global__ __launch_bounds__(256) void gemm_bf16(
    const ushort* __restrict__ X, const ushort* __restrict__ WT,
    const float* __restrict__ bias, const float* __restrict__ esc,
    const float* __restrict__ esh, float* __restrict__ C,
    ushort* __restrict__ Cb, int N, int K)
{
    __shared__ ushort Xs[2][128][40];
    __shared__ ushort Ws[2][128][40];
    const int tid = threadIdx.x;
    const int lane = tid & 63, wave = tid >> 6;
    const int wr = wave >> 1, wc = wave & 1;
    const int bm = blockIdx.y * 128, bn = blockIdx.x * 128;
    const int sr = tid >> 1, sh = tid & 1;

    f32x4 acc[4][4];
#pragma unroll
    for (int m=0;m<4;m++)
#pragma unroll
      for (int n=0;n<4;n++) acc[m][n] = (f32x4){0.f,0.f,0.f,0.f};

    float4 xv0, xv1, wv0, wv1;
    {
        const float4* xp = (const float4*)(X + (size_t)(bm+sr)*K + sh*16);
        xv0 = xp[0]; xv1 = xp[1];
        const float4* wp = (const float4*)(WT + (size_t)(bn+sr)*K + sh*16);
        wv0 = wp[0]; wv1 = wp[1];
    }
    {
        float4* dx = (float4*)&Xs[0][sr][sh*16]; dx[0] = xv0; dx[1] = xv1;
        float4* dw = (float4*)&Ws[0][sr][sh*16]; dw[0] = wv0; dw[1] = wv1;
    }
    __syncthreads();

    const int ko = (lane >> 4) * 8;
    const int fr = lane & 15;
    int cur = 0;
    for (int k0 = 0; k0 < K; k0 += 32) {
        int kn = k0 + 32;
        if (kn < K) {
            const float4* xp = (const float4*)(X + (size_t)(bm+sr)*K + kn + sh*16);
            xv0 = xp[0]; xv1 = xp[1];
            const float4* wp = (const float4*)(WT + (size_t)(bn+sr)*K + kn + sh*16);
            wv0 = wp[0]; wv1 = wp[1];
        }
        bf16x8 af[4], bfr[4];
#pragma unroll
        for (int m=0;m<4;m++) af[m]  = *(const bf16x8*)&Xs[cur][wr*64 + m*16 + fr][ko];
#pragma unroll
        for (int n=0;n<4;n++) bfr[n] = *(const bf16x8*)&Ws[cur][wc*64 + n*16 + fr][ko];
#pragma unroll
        for (int m=0;m<4;m++)
#pragma unroll
            for (int n=0;n<4;n++)
                acc[m][n] = __builtin_amdgcn_mfma_f32_16x16x32_bf16(af[m], bfr[n], acc[m][n], 0, 0, 0);
        if (kn < K) {
            int nb = cur ^ 1;
            float4* dx = (float4*)&Xs[nb][sr][sh*16]; dx[0] = xv0; dx[1] = xv1;
            float4* dw = (float4*)&Ws[nb][sr][sh*16]; dw[0] = wv0; dw[1] = wv1;
        }
        __syncthreads();
        cur ^= 1;
    }
    const int cr = (lane >> 4) * 4, cc = lane & 15;
#pragma unroll
    for (int m=0;m<4;m++) {
#pragma unroll
        for (int n=0;n<4;n++) {
            int gn = bn + wc*64 + n*16 + cc;
            float bb = bias[gn];
            float s0 = 0.f, s1 = 0.f;
            if (EPI == 1) { s0 = esc[gn]; s1 = esh[gn]; }
#pragma unroll
            for (int r=0;r<4;r++) {
                int gm = bm + wr*64 + m*16 + cr + r;
                float v = acc[m][n][r] + bb;
                if (EPI == 1) v = s0*v + s1;
                size_t off = (size_t)gm*N + gn;
                C[off] = v;
                if (EPI == 2) Cb[off] = f2b(v);
            }
        }
    }
}

// ---------------- weight transpose + f32->bf16: WT[n][k] = bf16(W[k][n]) ----------------
__global__ __launch_bounds__(256) void transW(const float* __restrict__ W,
    ushort* __restrict__ WT, int K, int N)
{
    __shared__ float tile[32][33];
    int n0 = blockIdx.x*32, k0 = blockIdx.y*32;
    int tx = threadIdx.x & 31, ty8 = threadIdx.x >> 5;
#pragma unroll
    for (int i=0;i<4;i++)
        tile[ty8 + i*8][tx] = W[(size_t)(k0 + ty8 + i*8)*N + n0 + tx];
    __syncthreads();
#pragma unroll
    for (int i=0;i<4;i++) {
        int n = ty8 + i*8;
        WT[(size_t)(n0+n)*K + k0 + tx] = f2b(tile[tx][n]);
    }
}

// ---------------- LayerNorm + relu + add, numpy-f32-exact; WB=1 also writes bf16 mirror ----------------
template<int WB>
__global__ __launch_bounds__(64) void ln_np(const float* __restrict__ t,
    float* __restrict__ h, ushort* __restrict__ hb,
    const float* __restrict__ g, const float* __restrict__ be)
{
    const int row = blockIdx.x;
    const float* tr = t + (long)row*DE;
    float* hr = h + (long)row*DE;
    __shared__ float bs[16];
    __shared__ float mv[2];
    const int l = threadIdx.x;

    if (l < 16) {
        const float* p = tr + l*128;
        float r[8];
#pragma unroll
        for (int j=0;j<8;j++) r[j] = p[j];
        for (int i=8;i<128;i+=8)
#pragma unroll
            for (int j=0;j<8;j++) r[j] = __fadd_rn(r[j], p[i+j]);
        float tA = __fadd_rn(__fadd_rn(r[0],r[1]), __fadd_rn(r[2],r[3]));
        float tB = __fadd_rn(__fadd_rn(r[4],r[5]), __fadd_rn(r[6],r[7]));
        bs[l] = __fadd_rn(tA, tB);
    }
    __syncthreads();
    if (l == 0) {
        float s8[8], s4[4], s2[2];
#pragma unroll
        for (int i=0;i<8;i++) s8[i] = __fadd_rn(bs[2*i], bs[2*i+1]);
#pragma unroll
        for (int i=0;i<4;i++) s4[i] = __fadd_rn(s8[2*i], s8[2*i+1]);
#pragma unroll
        for (int i=0;i<2;i++) s2[i] = __fadd_rn(s4[2*i], s4[2*i+1]);
        mv[0] = __fdiv_rn(__fadd_rn(s2[0], s2[1]), 2048.0f);
    }
    __syncthreads();
    const float m = mv[0];
    if (l < 16) {
        const float* p = tr + l*128;
        float r[8];
#pragma unroll
        for (int j=0;j<8;j++) { float d = __fsub_rn(p[j], m); r[j] = __fmul_rn(d, d); }
        for (int i=8;i<128;i+=8)
#pragma unroll
            for (int j=0;j<8;j++) {
                float d = __fsub_rn(p[i+j], m);
                r[j] = __fadd_rn(r[j], __fmul_rn(d, d));
            }
        float tA = __fadd_rn(__fadd_rn(r[0],r[1]), __fadd_rn(r[2],r[3]));
        float tB = __fadd_rn(__fadd_rn(r[4],r[5]), __fadd_rn(r[6],r[7]));
        bs[l] = __fadd_rn(tA, tB);
    }
    __syncthreads();
    if (l == 0) {
        float s8[8], s4[4], s2[2];
#pragma unroll
        for (int i=0;i<8;i++) s8[i] = __fadd_rn(bs[2*i], bs[2*i+1]);
#pragma unroll
        for (int i=0;i<4;i++) s4[i] = __fadd_rn(s8[2*i], s8[2*i+1]);
#pragma unroll
        for (int i=0;i<2;i++) s2[i] = __fadd_rn(s4[2*i], s4[2*i+1]);
        float v = __fdiv_rn(__fadd_rn(s2[0], s2[1]), 2048.0f);
        mv[1] = __fdiv_rn(1.0f, __fsqrt_rn(__fadd_rn(v, EPSLN)));
    }
    __syncthreads();
    const float rs = mv[1];
    ushort* hbr = (WB ? hb + (long)row*DE : nullptr);
    for (int j = l; j < DE; j += 64) {
        float u = __fadd_rn(__fmul_rn(__fmul_rn(__fsub_rn(tr[j], m), rs), g[j]), be[j]);
        float r = u > 0.0f ? u : 0.0f;
        float nh = __fadd_rn(hr[j], r);
        hr[j] = nh;
        if (WB) hbr[j] = f2b(nh);
    }
}

// ---------------- IdxEmbedding, np-f32 ----------------
__global__ __launch_bounds__(128) void idx_embed_np(const int* __restrict__ bidx,
    const float* __restrict__ lay, const float* __restrict__ lty, const float* __restrict__ wty,
    const float* __restrict__ fw, const float* __restrict__ fb,
    const float* __restrict__ ow, const float* __restrict__ ob,
    float* __restrict__ oidx)
{
    const int row = blockIdx.x;
    __shared__ float emb[3*HID+3];
    __shared__ float fcv[HID];
    const int t = threadIdx.x;
    int c0 = bidx[row*6+0], c1 = bidx[row*6+1], c2 = bidx[row*6+2];
    emb[t]       = lay[c0*HID + t];
    emb[HID+t]   = lty[c1*HID + t];
    emb[2*HID+t] = wty[c2*HID + t];
    if (t < 3) emb[3*HID+t] = (float)bidx[row*6+3+t];
    __syncthreads();
    {
        float acc = 0.0f;
        for (int k = 0; k < 3*HID+3; ++k)
            acc = fmaf(emb[k], fw[k*HID + t], acc);
        fcv[t] = __fadd_rn(acc, fb[t]);
    }
    __syncthreads();
    if (t < ODIM) {
        float acc = 0.0f;
        for (int k = 0; k < HID; ++k)
            acc = fmaf(fcv[k], ow[k*ODIM + t], acc);
        oidx[(long)row*ODIM + t] = __fadd_rn(acc, ob[t]);
    }
}

// ---------------- squared row norms, numpy pairwise (4 blocks of 128) ----------------
__global__ __launch_bounds__(256) void sqnorm_np(const float* __restrict__ a, int nrows,
    float* __restrict__ outv)
{
    int rI = blockIdx.x*256 + threadIdx.x;
    if (rI >= nrows) return;
    const float* p = a + (long)rI*ED;
    float B[4];
#pragma unroll
    for (int b = 0; b < 4; ++b) {
        const float* q = p + b*128;
        float r[8];
#pragma unroll
        for (int j=0;j<8;j++) r[j] = __fmul_rn(q[j], q[j]);
        for (int i=8;i<128;i+=8)
#pragma unroll
            for (int j=0;j<8;j++) r[j] = __fadd_rn(r[j], __fmul_rn(q[i+j], q[i+j]));
        float tA = __fadd_rn(__fadd_rn(r[0],r[1]), __fadd_rn(r[2],r[3]));
        float tB = __fadd_rn(__fadd_rn(r[4],r[5]), __fadd_rn(r[6],r[7]));
        B[b] = __fadd_rn(tA, tB);
    }
    outv[rI] = __fadd_rn(__fadd_rn(B[0], B[1]), __fadd_rn(B[2], B[3]));
}

// ---------------- final argmin across 16 column blocks ----------------
__global__ __launch_bounds__(256) void vq_reduce(const float* __restrict__ pval,
    const int* __restrict__ pidx, int* __restrict__ idxw, float* __restrict__ idxf,
    int* __restrict__ cnt)
{
    int r = blockIdx.x*256 + threadIdx.x;
    const float* pv = pval + (long)r*16;
    const int*   pi = pidx + (long)r*16;
    float best = pv[0]; int bj = pi[0];
#pragma unroll
    for (int c = 1; c < 16; ++c) {
        float v = pv[c]; int ii = pi[c];
        if (v < best || (v == best && ii < bj)) { best = v; bj = ii; }
    }
    idxw[r] = bj;
    idxf[r] = (float)bj;
    atomicAdd(&cnt[bj], 1);
}

// ---------------- z_q_st + bf16 mirror + SSE accumulation ----------------
__global__ __launch_bounds__(256) void zq_loss(const int* __restrict__ idxw,
    const float* __restrict__ cbk, const float* __restrict__ z_e,
    float* __restrict__ zq_out, ushort* __restrict__ zqb, double* __restrict__ sse)
{
    double local = 0.0;
    const long total = (long)NZF*ED;
    for (long g = (long)blockIdx.x*256 + threadIdx.x; g < total; g += (long)gridDim.x*256) {
        int p = (int)(g >> 9);
        int e = (int)(g & 511);
        float q = cbk[(long)idxw[p]*ED + e];
        float z = z_e[g];
        float d = __fsub_rn(q, z);
        float o = __fadd_rn(z, d);
        zq_out[g] = o;
        zqb[g] = f2b(o);
        local += (double)d * (double)d;
    }
    for (int off = 32; off > 0; off >>= 1) local += __shfl_down(local, off);
    __shared__ double red[4];
    int wid = threadIdx.x >> 6, lane = threadIdx.x & 63;
    if (lane == 0) red[wid] = local;
    __syncthreads();
    if (threadIdx.x == 0) atomicAdd(sse, red[0]+red[1]+red[2]+red[3]);
}

// ---------------- loss + perplexity ----------------
__global__ __launch_bounds__(256) void finalize(const int* __restrict__ cnt,
    const double* __restrict__ sse, float* __restrict__ d_out)
{
    double s = 0.0;
    for (int j = threadIdx.x; j < NE; j += 256) {
        double e = (double)cnt[j] / (double)NZF;
        s += e * log(e + 1e-10);
    }
    for (int off = 32; off > 0; off >>= 1) s += __shfl_down(s, off);
    __shared__ double red[4];
    int wid = threadIdx.x >> 6, lane = threadIdx.x & 63;
    if (lane == 0) red[wid] = s;
    __syncthreads();
    if (threadIdx.x == 0) {
        double st = red[0]+red[1]+red[2]+red[3];
        d_out[0]        = (float)(1.25 * sse[0] / (double)((long)BB*DE));
        d_out[PERP_OFF] = (float)exp(-st);
    }
}

extern "C" void kernel_launch(void* const* d_in, const int* in_sizes, int n_in,
                              void* d_out_v, int out_size, void* d_ws, size_t ws_size,
                              hipStream_t stream)
{
    const float* x         = (const float*)d_in[0];
    const int*   bidx      = (const int*)  d_in[1];
    const float* scale     = (const float*)d_in[2];
    const float* shift     = (const float*)d_in[3];
    const float* enc_in_w  = (const float*)d_in[4];
    const float* enc_in_b  = (const float*)d_in[5];
    const float* enc_res_w = (const float*)d_in[6];
    const float* enc_res_b = (const float*)d_in[7];
    const float* enc_ln_g  = (const float*)d_in[8];
    const float* enc_ln_b  = (const float*)d_in[9];
    const float* lay       = (const float*)d_in[10];
    const float* lty       = (const float*)d_in[11];
    const float* wty       = (const float*)d_in[12];
    const float* fcw       = (const float*)d_in[13];
    const float* fcb       = (const float*)d_in[14];
    const float* oww       = (const float*)d_in[15];
    const float* owb       = (const float*)d_in[16];
    const float* catw      = (const float*)d_in[17];
    const float* catb      = (const float*)d_in[18];
    const float* cbk       = (const float*)d_in[19];
    const float* dec_in_w  = (const float*)d_in[20];
    const float* dec_in_b  = (const float*)d_in[21];
    const float* dec_res_w = (const float*)d_in[22];
    const float* dec_res_b = (const float*)d_in[23];
    const float* dec_ln_g  = (const float*)d_in[24];
    const float* dec_ln_b  = (const float*)d_in[25];
    const float* dec_out_w = (const float*)d_in[26];
    const float* dec_out_b = (const float*)d_in[27];
    float* out = (float*)d_out_v;

    char* w = (char*)d_ws;
    auto alloc = [&](size_t bytes) {
        char* p = w;
        w += (bytes + 255) & ~(size_t)255;
        return p;
    };
    float*  xs   = (float*)alloc((size_t)BB*INW*4);     // dead after enc_in GEMM
    float*  h    = (float*)alloc((size_t)BB*DE*4);
    float*  t    = (float*)alloc((size_t)BB*DE*4);
    float*  oidx = (float*)alloc((size_t)BB*ODIM*4);
    int*    idxw = (int*)  alloc((size_t)NZF*4);
    float*  szv  = (float*)alloc((size_t)NZF*4);
    float*  scv  = (float*)alloc((size_t)NE*4);
    int*    cnt  = (int*)  alloc((size_t)NE*4);
    double* sse  = (double*)alloc(8);
    float*  cbT  = (float*)alloc((size_t)ED*NE*4);      // 4MB transposed codebook
    ushort* zqb  = (ushort*)alloc((size_t)BB*DE*2);     // bf16 z_q_st
    ushort* hb   = (ushort*)alloc((size_t)BB*DE*2);     // bf16 decoder hidden
    ushort* wt1  = (ushort*)alloc((size_t)DE*DE*2);     // dec_in_w^T bf16
    ushort* wt2  = (ushort*)alloc((size_t)DE*DE*2);     // dec_res_w^T bf16
    ushort* wt3  = (ushort*)alloc((size_t)INW*DE*2);    // dec_out_w^T bf16
    // aliases:
    float*  z_e  = t;
    float*  pval = (float*)xs;                          // NZF*16*4 (xs dead)
    int*    pidx = (int*)(xs + (size_t)NZF*16);

    hipMemsetAsync(cnt, 0, (size_t)NE*4, stream);
    hipMemsetAsync(sse, 0, 8, stream);

    dim3 gDE(DE/128, BB/128);    // (16,64)
    dim3 gIN(INW/128, BB/128);   // (8,64)
    dim3 gVQ(NE/128, NZF/128);   // (16,256)

    // ---- encoder: numpy-f32-exact semantics ----
    prep_xs<<<2048, 256, 0, stream>>>(x, scale, shift, xs);
    gemm_f32<0><<<gDE, 512, 0, stream>>>(xs, INW, nullptr, 0, enc_in_w, enc_in_b, h, DE);
    for (int r = 0; r < NRES; ++r) {
        gemm_f32<0><<<gDE, 512, 0, stream>>>(h, DE, nullptr, 0, enc_res_w, enc_res_b, t, DE);
        ln_np<0><<<BB, 64, 0, stream>>>(t, h, nullptr, enc_ln_g, enc_ln_b);
    }
    idx_embed_np<<<BB, 128, 0, stream>>>(bidx, lay, lty, wty, fcw, fcb, oww, owb, oidx);
    gemm_f32<1><<<gDE, 512, 0, stream>>>(h, DE, oidx, ODIM, catw, catb, z_e, DE);
    // ---- VQ: numpy-f32 dists + first-min argmin ----
    transCB<<<dim3(NE/32, ED/32), 256, 0, stream>>>(cbk, cbT);
    sqnorm_np<<<NZF/256, 256, 0, stream>>>(z_e, NZF, szv);
    sqnorm_np<<<NE/256, 256, 0, stream>>>(cbk, NE, scv);
    vq128<<<gVQ, 512, 0, stream>>>(z_e, cbT, szv, scv, pval, pidx);
    vq_reduce<<<NZF/256, 256, 0, stream>>>(pval, pidx, idxw, out + IDX_OFF, cnt);
    zq_loss<<<2048, 256, 0, stream>>>(idxw, cbk, z_e, out + ZQ_OFF, zqb, sse);
    finalize<<<1, 256, 0, stream>>>(cnt, sse, out);
    // ---- decoder: bf16 MFMA (loose thresholds) ----
    transW<<<dim3(DE/32, DE/32), 256, 0, stream>>>(dec_in_w,  wt1, DE, DE);
    transW<<<dim3(DE/32, DE/32), 256, 0, stream>>>(dec_res_w, wt2, DE, DE);
    transW<<<dim3(INW/32, DE/32), 256, 0, stream>>>(dec_out_w, wt3, DE, INW);
    gemm_bf16<2><<<gDE, 256, 0, stream>>>(zqb, wt1, dec_in_b, nullptr, nullptr, h, hb, DE, DE);
    for (int r = 0; r < NRES; ++r) {
        gemm_bf16<0><<<gDE, 256, 0, stream>>>(hb, wt2, dec_res_b, nullptr, nullptr, t, nullptr, DE, DE);
        ln_np<1><<<BB, 64, 0, stream>>>(t, h, hb, dec_ln_g, dec_ln_b);
    }
    gemm_bf16<1><<<gIN, 256, 0, stream>>>(hb, wt3, dec_out_b, scale, shift, out + XHAT_OFF, nullptr, INW, DE);
}